// Round 7
// baseline (3898.417 us; speedup 1.0000x reference)
//
#include <hip/hip_runtime.h>

#define BB 4
#define NN 2048
#define DD 256
#define HH 8
#define RR 64
#define DHH 32
#define KSP 32
#define ROWS (BB*NN)   // 8192
#define NEG_INF (-3.0e38f)
#define TK 16          // keys per staged tile
#define TSTR 36        // padded LDS row stride (floats): 2-way bank alias only

// ---------------- K1: h = (x @ U_np) @ V_np + b_np ----------------
__global__ __launch_bounds__(64) void k_node_proj(
    const float* __restrict__ x, const float* __restrict__ U,
    const float* __restrict__ V, const float* __restrict__ bias,
    float* __restrict__ h)
{
    const int row = blockIdx.x, lane = threadIdx.x;
    __shared__ float xs[DD];
    __shared__ float ts[RR];
    const float* xr = x + (size_t)row * DD;
    { float4 t4 = ((const float4*)xr)[lane];
      xs[lane*4]=t4.x; xs[lane*4+1]=t4.y; xs[lane*4+2]=t4.z; xs[lane*4+3]=t4.w; }
    __syncthreads();
    float t = 0.f;
    for (int d = 0; d < DD; ++d) t = fmaf(xs[d], U[d*RR + lane], t);
    ts[lane] = t;
    __syncthreads();
    float a[4];
    #pragma unroll
    for (int j = 0; j < 4; ++j) a[j] = bias[lane + 64*j];
    for (int r = 0; r < RR; ++r) {
        float tv = ts[r];
        const float* Vr = V + r*DD + lane;
        #pragma unroll
        for (int j = 0; j < 4; ++j) a[j] = fmaf(tv, Vr[64*j], a[j]);
    }
    float* hr = h + (size_t)row * DD;
    #pragma unroll
    for (int j = 0; j < 4; ++j) hr[lane + 64*j] = a[j];
}

// ---------------- K2: q,k,v = lowrank(h), kept in [B,N,D] layout ----------------
__global__ __launch_bounds__(64) void k_qkv(
    const float* __restrict__ h,
    const float* __restrict__ Uq, const float* __restrict__ Vq,
    const float* __restrict__ Uk, const float* __restrict__ Vk,
    const float* __restrict__ Uv, const float* __restrict__ Vv,
    float* __restrict__ q, float* __restrict__ k, float* __restrict__ v)
{
    const int row = blockIdx.x, lane = threadIdx.x;
    __shared__ float hs[DD];
    __shared__ float tq[RR], tk[RR], tvv[RR];
    const float* hr = h + (size_t)row * DD;
    { float4 t4 = ((const float4*)hr)[lane];
      hs[lane*4]=t4.x; hs[lane*4+1]=t4.y; hs[lane*4+2]=t4.z; hs[lane*4+3]=t4.w; }
    __syncthreads();
    float aq=0.f, ak=0.f, av=0.f;
    for (int d = 0; d < DD; ++d) {
        float hv = hs[d];
        aq = fmaf(hv, Uq[d*RR + lane], aq);
        ak = fmaf(hv, Uk[d*RR + lane], ak);
        av = fmaf(hv, Uv[d*RR + lane], av);
    }
    tq[lane]=aq; tk[lane]=ak; tvv[lane]=av;
    __syncthreads();
    float oq[4], ok[4], ov[4];
    #pragma unroll
    for (int j = 0; j < 4; ++j) { oq[j]=0.f; ok[j]=0.f; ov[j]=0.f; }
    for (int r = 0; r < RR; ++r) {
        float sq=tq[r], sk=tk[r], sv=tvv[r];
        const int base = r*DD + lane;
        #pragma unroll
        for (int j = 0; j < 4; ++j) {
            oq[j] = fmaf(sq, Vq[base + 64*j], oq[j]);
            ok[j] = fmaf(sk, Vk[base + 64*j], ok[j]);
            ov[j] = fmaf(sv, Vv[base + 64*j], ov[j]);
        }
    }
    float* qr = q + (size_t)row * DD;
    float* kr = k + (size_t)row * DD;
    float* vr = v + (size_t)row * DD;
    #pragma unroll
    for (int j = 0; j < 4; ++j) {
        qr[lane + 64*j] = oq[j];
        kr[lane + 64*j] = ok[j];
        vr[lane + 64*j] = ov[j];
    }
}

// dot over 32 dims; IDENTICAL rounding order wherever scores are computed
__device__ __forceinline__ float dot32r(const float4* qa, const float4* kr) {
    float s0=0.f, s1=0.f, s2=0.f, s3=0.f;
    #pragma unroll
    for (int i = 0; i < 8; ++i) {
        float4 kv = kr[i];
        s0 = fmaf(qa[i].x, kv.x, s0);
        s1 = fmaf(qa[i].y, kv.y, s1);
        s2 = fmaf(qa[i].z, kv.z, s2);
        s3 = fmaf(qa[i].w, kv.w, s3);
    }
    return (s0+s1)+(s2+s3);
}

// branchless exact insert into sorted-ascending 32-list (med3 identity)
#define INSERT32(tp, sm) do { \
    _Pragma("unroll") for (int _i = 0; _i < 31; ++_i) \
        (tp)[_i] = __builtin_amdgcn_fmed3f((sm), (tp)[_i], (tp)[_i+1]); \
    (tp)[31] = fmaxf((tp)[31], (sm)); \
} while (0)

// cooperative 16-row tile staging: issue (global->regs) / write (regs->LDS)
// lane -> (row = lane>>2, col4 = lane&3); two float4 per lane cover 16x32 tile
__device__ __forceinline__ void stage_issue(
    const float* __restrict__ base, int gj, int lane, float4& a, float4& b)
{
    const float* p = base + (size_t)(gj + (lane >> 2)) * DD + (lane & 3) * 4;
    a = *(const float4*)p;
    b = *(const float4*)(p + 16);
}
__device__ __forceinline__ void stage_write(
    float* slot, int lane, const float4& a, const float4& b)
{
    float* p = slot + (lane >> 2) * TSTR + (lane & 3) * 4;
    *(float4*)p = a;
    *(float4*)(p + 16) = b;
}

// ---------------- K3: sparse top-32 attention, lane = query, LDS-staged ----------------
// 4 waves/block, 64 queries/block (one per lane). Wave w scans keys [512w,512w+512)
// in 32 tiles of 16 keys, staged to a per-wave 4-slot LDS ring (issue-early/
// write-late). Pass 1: exact per-lane top-32 (med3 insert). 4-way merge -> exact
// m and thr. Pass 2: re-staged K + V tiles; recompute scores (identical rounding),
// select s>=thr, broadcast-FMA V rows from LDS. Cross-wave combine in LDS.
__global__ __launch_bounds__(256, 2) void k_attn(
    const float* __restrict__ q, const float* __restrict__ kx,
    const float* __restrict__ vx, float* __restrict__ o)
{
    __shared__ float tl[4][32][64];          // 32 KB: top lists, then acc partials
    __shared__ float swl[4][64];             // 1 KB
    __shared__ float ring[4][4][TK][TSTR];   // 36 KB: per-wave 4-slot tile ring
    const int lane = threadIdx.x & 63;
    const int wv   = threadIdx.x >> 6;
    const int blk  = blockIdx.x;
    const int tile = blk & 31;
    const int head = (blk >> 5) & 7;
    const int b    = blk >> 8;
    const int n    = tile*64 + lane;

    const float* qp    = q  + ((size_t)(b*NN + n))*DD + head*DHH;
    const float* kbase = kx + (size_t)b*NN*DD + head*DHH;
    const float* vbase = vx + (size_t)b*NN*DD + head*DHH;
    const float scale = 0.17677669529663687f;  // 1/sqrt(32)

    float4 qa[8];
    #pragma unroll
    for (int i = 0; i < 8; ++i) qa[i] = ((const float4*)qp)[i];

    const int j0 = wv*512;

    // ---- pass 1: exact top-32 over this wave's 512 keys, K from LDS ring ----
    float tp[32];
    #pragma unroll
    for (int i = 0; i < 32; ++i) tp[i] = NEG_INF;

    {
        float4 a0,b0,a1,b1;
        stage_issue(kbase, j0,      lane, a0, b0);
        stage_issue(kbase, j0 + TK, lane, a1, b1);
        stage_write(&ring[wv][0][0][0], lane, a0, b0);
        stage_write(&ring[wv][1][0][0], lane, a1, b1);
        for (int t = 0; t < 32; ++t) {
            float4 na, nb;
            const int nt = t + 2;
            if (nt < 32) stage_issue(kbase, j0 + nt*TK, lane, na, nb);
            const float* sl = &ring[wv][t & 3][0][0];
            #pragma unroll
            for (int jj = 0; jj < TK; ++jj) {
                float s = dot32r(qa, (const float4*)(sl + jj*TSTR)) * scale;
                INSERT32(tp, s);
            }
            if (nt < 32) stage_write(&ring[wv][nt & 3][0][0], lane, na, nb);
        }
    }
    #pragma unroll
    for (int i = 0; i < 32; ++i) tl[wv][i][lane] = tp[i];
    __syncthreads();

    // ---- merge 4 sorted lists: exact m (pick 0) and thr (pick 31) ----
    int i0=31, i1=31, i2=31, i3=31;
    float m = NEG_INF, thr = NEG_INF;
    for (int p = 0; p < 32; ++p) {
        float v0 = tl[0][i0][lane];
        float v1 = tl[1][i1][lane];
        float v2 = tl[2][i2][lane];
        float v3 = tl[3][i3][lane];
        float vm = fmaxf(fmaxf(v0,v1), fmaxf(v2,v3));
        if (p == 0) m = vm;
        thr = vm;
        if      (vm == v0) --i0;
        else if (vm == v1) --i1;
        else if (vm == v2) --i2;
        else               --i3;
    }
    __syncthreads();   // all merges done reading tl before acc overwrite later

    // ---- pass 2: rescan (identical rounding), select s>=thr, PV from LDS ----
    float acc[32];
    #pragma unroll
    for (int d = 0; d < 32; ++d) acc[d] = 0.f;
    float sw = 0.f;
    {
        // K tiles -> slots {0,1}; V tiles -> slots {2,3}; depth-1 prefetch
        float4 ka, kb2, va, vb;
        stage_issue(kbase, j0, lane, ka, kb2);
        stage_issue(vbase, j0, lane, va, vb);
        stage_write(&ring[wv][0][0][0], lane, ka, kb2);
        stage_write(&ring[wv][2][0][0], lane, va, vb);
        for (int t = 0; t < 32; ++t) {
            float4 nka, nkb, nva, nvb;
            const int nt = t + 1;
            if (nt < 32) {
                stage_issue(kbase, j0 + nt*TK, lane, nka, nkb);
                stage_issue(vbase, j0 + nt*TK, lane, nva, nvb);
            }
            const float* ks = &ring[wv][t & 1][0][0];
            const float* vs = &ring[wv][2 + (t & 1)][0][0];
            #pragma unroll
            for (int jj = 0; jj < TK; ++jj) {
                float s = dot32r(qa, (const float4*)(ks + jj*TSTR)) * scale;
                bool sel = (s >= thr);
                if (__any(sel)) {
                    float w = sel ? __expf(s - m) : 0.f;
                    sw += w;
                    const float4* vrow = (const float4*)(vs + jj*TSTR);
                    #pragma unroll
                    for (int i = 0; i < 8; ++i) {
                        float4 vv = vrow[i];
                        acc[4*i]   = fmaf(w, vv.x, acc[4*i]);
                        acc[4*i+1] = fmaf(w, vv.y, acc[4*i+1]);
                        acc[4*i+2] = fmaf(w, vv.z, acc[4*i+2]);
                        acc[4*i+3] = fmaf(w, vv.w, acc[4*i+3]);
                    }
                }
            }
            if (nt < 32) {
                stage_write(&ring[wv][nt & 1][0][0], lane, nka, nkb);
                stage_write(&ring[wv][2 + (nt & 1)][0][0], lane, nva, nvb);
            }
        }
    }

    #pragma unroll
    for (int d = 0; d < 32; ++d) tl[wv][d][lane] = acc[d];
    swl[wv][lane] = sw;
    __syncthreads();

    // ---- combine across waves: wave wv writes dims [8wv, 8wv+8) ----
    float swsum = swl[0][lane] + swl[1][lane] + swl[2][lane] + swl[3][lane];
    float inv = 1.0f / swsum;
    float* orow = o + ((size_t)(b*NN + n))*DD + head*DHH;
    #pragma unroll
    for (int dd = 0; dd < 8; ++dd) {
        int d = 8*wv + dd;
        float sv = tl[0][d][lane] + tl[1][d][lane] + tl[2][d][lane] + tl[3][d][lane];
        orow[d] = sv * inv;
    }
}

// ---------------- K4: out_pre = lowrank(lowrank(o)) ----------------
__global__ __launch_bounds__(64) void k_out_proj(
    const float* __restrict__ o,
    const float* __restrict__ Uo,  const float* __restrict__ Vo,  const float* __restrict__ bo,
    const float* __restrict__ Uop, const float* __restrict__ Vop, const float* __restrict__ bop,
    float* __restrict__ outp)
{
    const int row = blockIdx.x, lane = threadIdx.x;
    __shared__ float buf[DD];
    __shared__ float ts[RR];
    const float* orow = o + (size_t)row * DD;
    { float4 t4 = ((const float4*)orow)[lane];
      buf[lane*4]=t4.x; buf[lane*4+1]=t4.y; buf[lane*4+2]=t4.z; buf[lane*4+3]=t4.w; }
    __syncthreads();
    float t = 0.f;
    for (int d = 0; d < DD; ++d) t = fmaf(buf[d], Uo[d*RR + lane], t);
    ts[lane] = t;
    __syncthreads();
    float a[4];
    #pragma unroll
    for (int j = 0; j < 4; ++j) a[j] = bo[lane + 64*j];
    for (int r = 0; r < RR; ++r) {
        float tv = ts[r];
        #pragma unroll
        for (int j = 0; j < 4; ++j) a[j] = fmaf(tv, Vo[r*DD + lane + 64*j], a[j]);
    }
    __syncthreads();
    #pragma unroll
    for (int j = 0; j < 4; ++j) buf[lane + 64*j] = a[j];
    __syncthreads();
    float t2 = 0.f;
    for (int d = 0; d < DD; ++d) t2 = fmaf(buf[d], Uop[d*RR + lane], t2);
    __syncthreads();
    ts[lane] = t2;
    __syncthreads();
    float c[4];
    #pragma unroll
    for (int j = 0; j < 4; ++j) c[j] = bop[lane + 64*j];
    for (int r = 0; r < RR; ++r) {
        float tv = ts[r];
        #pragma unroll
        for (int j = 0; j < 4; ++j) c[j] = fmaf(tv, Vop[r*DD + lane + 64*j], c[j]);
    }
    float* orow_out = outp + (size_t)row * DD;
    #pragma unroll
    for (int j = 0; j < 4; ++j) orow_out[lane + 64*j] = c[j];
}

// ---------------- K5: BN batch stats per channel ----------------
__global__ __launch_bounds__(256) void k_bnstats(
    const float* __restrict__ outp, float* __restrict__ stats,
    const float* __restrict__ gamma, const float* __restrict__ beta)
{
    const int c = blockIdx.x, t = threadIdx.x;
    float s = 0.f, s2 = 0.f;
    for (int r = t; r < ROWS; r += 256) {
        float v = outp[(size_t)r*DD + c];
        s += v; s2 += v*v;
    }
    __shared__ float rs[256], rs2[256];
    rs[t] = s; rs2[t] = s2;
    __syncthreads();
    for (int step = 128; step; step >>= 1) {
        if (t < step) { rs[t] += rs[t+step]; rs2[t] += rs2[t+step]; }
        __syncthreads();
    }
    if (t == 0) {
        float mean = rs[0] * (1.0f/ROWS);
        float var  = rs2[0] * (1.0f/ROWS) - mean*mean;
        float inv  = rsqrtf(var + 1e-5f);
        float g = gamma[c], be = beta[c];
        stats[c]      = g * inv;
        stats[DD + c] = be - mean * g * inv;
    }
}

// ---------------- K6: apply BN (fp32 out) ----------------
__global__ __launch_bounds__(256) void k_bnapply(
    const float* __restrict__ outp, const float* __restrict__ stats,
    float* __restrict__ out)
{
    const size_t idx = (size_t)blockIdx.x * 256 + threadIdx.x;
    const int c = (int)(idx & (DD-1));
    out[idx] = outp[idx] * stats[c] + stats[DD + c];
}

extern "C" void kernel_launch(void* const* d_in, const int* in_sizes, int n_in,
                              void* d_out, int out_size, void* d_ws, size_t ws_size,
                              hipStream_t stream)
{
    (void)in_sizes; (void)n_in; (void)out_size; (void)ws_size;
    const float* x    = (const float*)d_in[0];
    const float* U_np = (const float*)d_in[1];
    const float* V_np = (const float*)d_in[2];
    const float* b_np = (const float*)d_in[3];
    const float* U_q  = (const float*)d_in[4];
    const float* V_q  = (const float*)d_in[5];
    const float* U_k  = (const float*)d_in[6];
    const float* V_k  = (const float*)d_in[7];
    const float* U_v  = (const float*)d_in[8];
    const float* V_v  = (const float*)d_in[9];
    const float* U_o  = (const float*)d_in[10];
    const float* V_o  = (const float*)d_in[11];
    const float* b_o  = (const float*)d_in[12];
    const float* U_op = (const float*)d_in[13];
    const float* V_op = (const float*)d_in[14];
    const float* b_op = (const float*)d_in[15];
    const float* gamma= (const float*)d_in[16];
    const float* beta = (const float*)d_in[17];

    float* ws  = (float*)d_ws;
    float* out = (float*)d_out;
    const size_t BUF = (size_t)ROWS * DD;     // 2,097,152 floats = 8 MB

    float* h    = out;        // K1 writes, K2 reads, dead after
    float* q    = ws;
    float* k    = ws + BUF;
    float* v    = ws + 2*BUF;
    float* o    = out;        // K3 writes (h dead), K4 reads
    float* outp = q;          // K4 writes (q dead), K5/K6 read
    float* stats= k;          // 512 floats (k dead)

    k_node_proj<<<ROWS, 64, 0, stream>>>(x, U_np, V_np, b_np, h);
    k_qkv<<<ROWS, 64, 0, stream>>>(h, U_q, V_q, U_k, V_k, U_v, V_v, q, k, v);
    k_attn<<<BB*HH*32, 256, 0, stream>>>(q, k, v, o);
    k_out_proj<<<ROWS, 64, 0, stream>>>(o, U_o, V_o, b_o, U_op, V_op, b_op, outp);
    k_bnstats<<<DD, 256, 0, stream>>>(outp, stats, gamma, beta);
    k_bnapply<<<ROWS, 256, 0, stream>>>(outp, stats, out);
}

// Round 8
// 1338.360 us; speedup vs baseline: 2.9128x; 2.9128x over previous
//
#include <hip/hip_runtime.h>

#define BB 4
#define NN 2048
#define DD 256
#define HH 8
#define RR 64
#define DHH 32
#define KSP 32
#define ROWS (BB*NN)   // 8192
#define NEG_INF (-3.0e38f)
#define SSTR 34        // score row stride (floats): 8B-aligned, conflict-free b64 reads
#define VSTR 36        // V row stride (floats): 16B-aligned for b128 writes

// ---------------- K1: h = (x @ U_np) @ V_np + b_np ----------------
__global__ __launch_bounds__(64) void k_node_proj(
    const float* __restrict__ x, const float* __restrict__ U,
    const float* __restrict__ V, const float* __restrict__ bias,
    float* __restrict__ h)
{
    const int row = blockIdx.x, lane = threadIdx.x;
    __shared__ float xs[DD];
    __shared__ float ts[RR];
    const float* xr = x + (size_t)row * DD;
    { float4 t4 = ((const float4*)xr)[lane];
      xs[lane*4]=t4.x; xs[lane*4+1]=t4.y; xs[lane*4+2]=t4.z; xs[lane*4+3]=t4.w; }
    __syncthreads();
    float t = 0.f;
    for (int d = 0; d < DD; ++d) t = fmaf(xs[d], U[d*RR + lane], t);
    ts[lane] = t;
    __syncthreads();
    float a[4];
    #pragma unroll
    for (int j = 0; j < 4; ++j) a[j] = bias[lane + 64*j];
    for (int r = 0; r < RR; ++r) {
        float tv = ts[r];
        const float* Vr = V + r*DD + lane;
        #pragma unroll
        for (int j = 0; j < 4; ++j) a[j] = fmaf(tv, Vr[64*j], a[j]);
    }
    float* hr = h + (size_t)row * DD;
    #pragma unroll
    for (int j = 0; j < 4; ++j) hr[lane + 64*j] = a[j];
}

// ---------------- K2: q,k,v = lowrank(h), kept in [B,N,D] layout ----------------
__global__ __launch_bounds__(64) void k_qkv(
    const float* __restrict__ h,
    const float* __restrict__ Uq, const float* __restrict__ Vq,
    const float* __restrict__ Uk, const float* __restrict__ Vk,
    const float* __restrict__ Uv, const float* __restrict__ Vv,
    float* __restrict__ q, float* __restrict__ k, float* __restrict__ v)
{
    const int row = blockIdx.x, lane = threadIdx.x;
    __shared__ float hs[DD];
    __shared__ float tq[RR], tk[RR], tvv[RR];
    const float* hr = h + (size_t)row * DD;
    { float4 t4 = ((const float4*)hr)[lane];
      hs[lane*4]=t4.x; hs[lane*4+1]=t4.y; hs[lane*4+2]=t4.z; hs[lane*4+3]=t4.w; }
    __syncthreads();
    float aq=0.f, ak=0.f, av=0.f;
    for (int d = 0; d < DD; ++d) {
        float hv = hs[d];
        aq = fmaf(hv, Uq[d*RR + lane], aq);
        ak = fmaf(hv, Uk[d*RR + lane], ak);
        av = fmaf(hv, Uv[d*RR + lane], av);
    }
    tq[lane]=aq; tk[lane]=ak; tvv[lane]=av;
    __syncthreads();
    float oq[4], ok[4], ov[4];
    #pragma unroll
    for (int j = 0; j < 4; ++j) { oq[j]=0.f; ok[j]=0.f; ov[j]=0.f; }
    for (int r = 0; r < RR; ++r) {
        float sq=tq[r], sk=tk[r], sv=tvv[r];
        const int base = r*DD + lane;
        #pragma unroll
        for (int j = 0; j < 4; ++j) {
            oq[j] = fmaf(sq, Vq[base + 64*j], oq[j]);
            ok[j] = fmaf(sk, Vk[base + 64*j], ok[j]);
            ov[j] = fmaf(sv, Vv[base + 64*j], ov[j]);
        }
    }
    float* qr = q + (size_t)row * DD;
    float* kr = k + (size_t)row * DD;
    float* vr = v + (size_t)row * DD;
    #pragma unroll
    for (int j = 0; j < 4; ++j) {
        qr[lane + 64*j] = oq[j];
        kr[lane + 64*j] = ok[j];
        vr[lane + 64*j] = ov[j];
    }
}

// 16-dim partial dot; same rounding everywhere: 4 partials, (s0+s1)+(s2+s3)
__device__ __forceinline__ float dot16(const float4* a, const float4* b) {
    float s0=0.f,s1=0.f,s2=0.f,s3=0.f;
    #pragma unroll
    for (int i = 0; i < 4; ++i) {
        s0 = fmaf(a[i].x, b[i].x, s0);
        s1 = fmaf(a[i].y, b[i].y, s1);
        s2 = fmaf(a[i].z, b[i].z, s2);
        s3 = fmaf(a[i].w, b[i].w, s3);
    }
    return (s0+s1)+(s2+s3);
}

// branchless exact insert into sorted-ascending 32-list (med3 identity)
#define INSERT32(tp, sm) do { \
    _Pragma("unroll") for (int _i = 0; _i < 31; ++_i) \
        (tp)[_i] = __builtin_amdgcn_fmed3f((sm), (tp)[_i], (tp)[_i+1]); \
    (tp)[31] = fmaxf((tp)[31], (sm)); \
} while (0)

// ---------------- K3: sparse top-32 attention, transposed-score structure ----
// 4 waves/block own 64 queries; wave w scans keys [512w,512w+512) in 16 chunks
// of 32 keys. Per chunk: lane=(key,d-half) holds K half-row in regs; Q half-rows
// via L1-cached vector loads; s = (part + shfl_xor(part,32))*scale (bit-exact in
// both halves/passes). Scores transposed through per-wave LDS [64q][32k]; lane=
// query does exact med3 top-32 insert. 4-way merge -> exact m,thr. Pass 2
// recomputes scores identically, selects s>=thr, PV from LDS-staged V chunk
// (wave-uniform broadcast reads). Cross-wave combine in LDS.
__global__ __launch_bounds__(256) void k_attn(
    const float* __restrict__ qx, const float* __restrict__ kx,
    const float* __restrict__ vx, float* __restrict__ o)
{
    __shared__ float sc[4][64*SSTR];   // 34.8 KB: scores / top-lists / acc
    __shared__ float vb[4][32*VSTR];   // 18.4 KB: V chunk per wave
    __shared__ float swl[4][64];       // 1 KB
    const int lane = threadIdx.x & 63;
    const int wv   = threadIdx.x >> 6;
    const int blk  = blockIdx.x;
    const int tile = blk & 31;
    const int head = (blk >> 5) & 7;
    const int b    = blk >> 8;

    const int key = lane & 31;           // key within chunk
    const int dhf = (lane >> 5) << 4;    // d-half float offset: 0 or 16

    const float* Qb = qx + ((size_t)(b*NN + tile*64))*DD + head*DHH + dhf;
    const float* Kb = kx + (size_t)b*NN*DD + head*DHH + dhf;
    const float* Vb = vx + (size_t)b*NN*DD + head*DHH;
    float* scw = sc[wv];
    float* vbw = vb[wv];
    const int j0 = wv*512;
    const float scale = 0.17677669529663687f;  // 1/sqrt(32)

    // ---------------- pass 1: exact per-query top-32 over wave's 512 keys ----
    float t[32];
    #pragma unroll
    for (int i = 0; i < 32; ++i) t[i] = NEG_INF;

    for (int c = 0; c < 16; ++c) {
        const int kk0 = j0 + c*32;
        float4 kr[4];
        { const float4* kp = (const float4*)(Kb + (size_t)(kk0 + key)*DD);
          #pragma unroll
          for (int i = 0; i < 4; ++i) kr[i] = kp[i]; }

        #pragma unroll 4
        for (int qi = 0; qi < 64; ++qi) {
            const float4* qp = (const float4*)(Qb + (size_t)qi*DD);
            float4 qr[4];
            #pragma unroll
            for (int i = 0; i < 4; ++i) qr[i] = qp[i];
            float part = dot16(qr, kr);
            float oth  = __shfl_xor(part, 32, 64);
            float s = (part + oth) * scale;
            if (lane < 32) scw[qi*SSTR + key] = s;
        }
        // read my query's 32 chunk scores, insert
        const float2* rp = (const float2*)(scw + lane*SSTR);
        float2 s2[16];
        #pragma unroll
        for (int i = 0; i < 16; ++i) s2[i] = rp[i];
        #pragma unroll
        for (int kk = 0; kk < 32; ++kk) {
            float s = (kk & 1) ? s2[kk>>1].y : s2[kk>>1].x;
            INSERT32(t, s);
        }
    }
    // publish top lists (overwrites score slice; same-wave ordering via lgkm)
    {
        float* tlw = scw;
        #pragma unroll
        for (int i = 0; i < 32; ++i) tlw[i*64 + lane] = t[i];
    }
    __syncthreads();

    // ---------------- merge 4 sorted lists: exact m (pick 0), thr (pick 31) --
    int i0=31, i1=31, i2=31, i3=31;
    float m = NEG_INF, thr = NEG_INF;
    for (int p = 0; p < 32; ++p) {
        float v0 = sc[0][i0*64 + lane];
        float v1 = sc[1][i1*64 + lane];
        float v2 = sc[2][i2*64 + lane];
        float v3 = sc[3][i3*64 + lane];
        float vm = fmaxf(fmaxf(v0,v1), fmaxf(v2,v3));
        if (p == 0) m = vm;
        thr = vm;
        if      (vm == v0) --i0;
        else if (vm == v1) --i1;
        else if (vm == v2) --i2;
        else               --i3;
    }
    __syncthreads();   // all waves done reading lists before slices reused

    // ---------------- pass 2: recompute scores, select s>=thr, PV ----------
    float acc[32];
    #pragma unroll
    for (int d = 0; d < 32; ++d) acc[d] = 0.f;
    float sw = 0.f;

    for (int c = 0; c < 16; ++c) {
        const int kk0 = j0 + c*32;
        // issue V chunk loads early (32 rows x 32 f; lane -> row lane>>1, half lane&1)
        float4 vr[4];
        { const float* vp = Vb + (size_t)(kk0 + (lane>>1))*DD + (lane&1)*16;
          #pragma unroll
          for (int r = 0; r < 4; ++r) vr[r] = ((const float4*)vp)[r]; }
        // K half-row
        float4 kr[4];
        { const float4* kp = (const float4*)(Kb + (size_t)(kk0 + key)*DD);
          #pragma unroll
          for (int i = 0; i < 4; ++i) kr[i] = kp[i]; }
        // scores (identical rounding to pass 1)
        #pragma unroll 4
        for (int qi = 0; qi < 64; ++qi) {
            const float4* qp = (const float4*)(Qb + (size_t)qi*DD);
            float4 qr[4];
            #pragma unroll
            for (int i = 0; i < 4; ++i) qr[i] = qp[i];
            float part = dot16(qr, kr);
            float oth  = __shfl_xor(part, 32, 64);
            float s = (part + oth) * scale;
            if (lane < 32) scw[qi*SSTR + key] = s;
        }
        // V regs -> LDS (after score writes; same-wave lgkm ordering)
        { float* wp = vbw + (lane>>1)*VSTR + (lane&1)*16;
          #pragma unroll
          for (int r = 0; r < 4; ++r) ((float4*)wp)[r] = vr[r]; }
        // my query's 32 scores
        const float2* rp = (const float2*)(scw + lane*SSTR);
        float2 s2[16];
        #pragma unroll
        for (int i = 0; i < 16; ++i) s2[i] = rp[i];
        // select + PV (V broadcast rows from LDS)
        #pragma unroll
        for (int kk = 0; kk < 32; ++kk) {
            float s = (kk & 1) ? s2[kk>>1].y : s2[kk>>1].x;
            bool sel = (s >= thr);
            float w = sel ? __expf(s - m) : 0.f;
            sw += w;
            if (__any(sel)) {
                const float4* vv = (const float4*)(vbw + kk*VSTR);
                #pragma unroll
                for (int i = 0; i < 8; ++i) {
                    float4 vvv = vv[i];
                    acc[4*i]   = fmaf(w, vvv.x, acc[4*i]);
                    acc[4*i+1] = fmaf(w, vvv.y, acc[4*i+1]);
                    acc[4*i+2] = fmaf(w, vvv.z, acc[4*i+2]);
                    acc[4*i+3] = fmaf(w, vvv.w, acc[4*i+3]);
                }
            }
        }
    }

    // publish partials (own slice; then barrier for cross-wave combine)
    #pragma unroll
    for (int d = 0; d < 32; ++d) scw[d*64 + lane] = acc[d];
    swl[wv][lane] = sw;
    __syncthreads();

    float swsum = swl[0][lane] + swl[1][lane] + swl[2][lane] + swl[3][lane];
    float inv = 1.0f / swsum;
    float* orow = o + ((size_t)(b*NN + tile*64 + lane))*DD + head*DHH;
    #pragma unroll
    for (int dd = 0; dd < 8; ++dd) {
        int d = 8*wv + dd;
        float sv = sc[0][d*64+lane] + sc[1][d*64+lane]
                 + sc[2][d*64+lane] + sc[3][d*64+lane];
        orow[d] = sv * inv;
    }
}

// ---------------- K4: out_pre = lowrank(lowrank(o)) ----------------
__global__ __launch_bounds__(64) void k_out_proj(
    const float* __restrict__ o,
    const float* __restrict__ Uo,  const float* __restrict__ Vo,  const float* __restrict__ bo,
    const float* __restrict__ Uop, const float* __restrict__ Vop, const float* __restrict__ bop,
    float* __restrict__ outp)
{
    const int row = blockIdx.x, lane = threadIdx.x;
    __shared__ float buf[DD];
    __shared__ float ts[RR];
    const float* orow = o + (size_t)row * DD;
    { float4 t4 = ((const float4*)orow)[lane];
      buf[lane*4]=t4.x; buf[lane*4+1]=t4.y; buf[lane*4+2]=t4.z; buf[lane*4+3]=t4.w; }
    __syncthreads();
    float t = 0.f;
    for (int d = 0; d < DD; ++d) t = fmaf(buf[d], Uo[d*RR + lane], t);
    ts[lane] = t;
    __syncthreads();
    float a[4];
    #pragma unroll
    for (int j = 0; j < 4; ++j) a[j] = bo[lane + 64*j];
    for (int r = 0; r < RR; ++r) {
        float tv = ts[r];
        #pragma unroll
        for (int j = 0; j < 4; ++j) a[j] = fmaf(tv, Vo[r*DD + lane + 64*j], a[j]);
    }
    __syncthreads();
    #pragma unroll
    for (int j = 0; j < 4; ++j) buf[lane + 64*j] = a[j];
    __syncthreads();
    float t2 = 0.f;
    for (int d = 0; d < DD; ++d) t2 = fmaf(buf[d], Uop[d*RR + lane], t2);
    __syncthreads();
    ts[lane] = t2;
    __syncthreads();
    float c[4];
    #pragma unroll
    for (int j = 0; j < 4; ++j) c[j] = bop[lane + 64*j];
    for (int r = 0; r < RR; ++r) {
        float tv = ts[r];
        #pragma unroll
        for (int j = 0; j < 4; ++j) c[j] = fmaf(tv, Vop[r*DD + lane + 64*j], c[j]);
    }
    float* orow_out = outp + (size_t)row * DD;
    #pragma unroll
    for (int j = 0; j < 4; ++j) orow_out[lane + 64*j] = c[j];
}

// ---------------- K5: BN batch stats per channel ----------------
__global__ __launch_bounds__(256) void k_bnstats(
    const float* __restrict__ outp, float* __restrict__ stats,
    const float* __restrict__ gamma, const float* __restrict__ beta)
{
    const int c = blockIdx.x, t = threadIdx.x;
    float s = 0.f, s2 = 0.f;
    for (int r = t; r < ROWS; r += 256) {
        float v = outp[(size_t)r*DD + c];
        s += v; s2 += v*v;
    }
    __shared__ float rs[256], rs2[256];
    rs[t] = s; rs2[t] = s2;
    __syncthreads();
    for (int step = 128; step; step >>= 1) {
        if (t < step) { rs[t] += rs[t+step]; rs2[t] += rs2[t+step]; }
        __syncthreads();
    }
    if (t == 0) {
        float mean = rs[0] * (1.0f/ROWS);
        float var  = rs2[0] * (1.0f/ROWS) - mean*mean;
        float inv  = rsqrtf(var + 1e-5f);
        float g = gamma[c], be = beta[c];
        stats[c]      = g * inv;
        stats[DD + c] = be - mean * g * inv;
    }
}

// ---------------- K6: apply BN (fp32 out) ----------------
__global__ __launch_bounds__(256) void k_bnapply(
    const float* __restrict__ outp, const float* __restrict__ stats,
    float* __restrict__ out)
{
    const size_t idx = (size_t)blockIdx.x * 256 + threadIdx.x;
    const int c = (int)(idx & (DD-1));
    out[idx] = outp[idx] * stats[c] + stats[DD + c];
}

extern "C" void kernel_launch(void* const* d_in, const int* in_sizes, int n_in,
                              void* d_out, int out_size, void* d_ws, size_t ws_size,
                              hipStream_t stream)
{
    (void)in_sizes; (void)n_in; (void)out_size; (void)ws_size;
    const float* x    = (const float*)d_in[0];
    const float* U_np = (const float*)d_in[1];
    const float* V_np = (const float*)d_in[2];
    const float* b_np = (const float*)d_in[3];
    const float* U_q  = (const float*)d_in[4];
    const float* V_q  = (const float*)d_in[5];
    const float* U_k  = (const float*)d_in[6];
    const float* V_k  = (const float*)d_in[7];
    const float* U_v  = (const float*)d_in[8];
    const float* V_v  = (const float*)d_in[9];
    const float* U_o  = (const float*)d_in[10];
    const float* V_o  = (const float*)d_in[11];
    const float* b_o  = (const float*)d_in[12];
    const float* U_op = (const float*)d_in[13];
    const float* V_op = (const float*)d_in[14];
    const float* b_op = (const float*)d_in[15];
    const float* gamma= (const float*)d_in[16];
    const float* beta = (const float*)d_in[17];

    float* ws  = (float*)d_ws;
    float* out = (float*)d_out;
    const size_t BUF = (size_t)ROWS * DD;     // 2,097,152 floats = 8 MB

    float* h    = out;        // K1 writes, K2 reads, dead after
    float* q    = ws;
    float* k    = ws + BUF;
    float* v    = ws + 2*BUF;
    float* o    = out;        // K3 writes (h dead), K4 reads
    float* outp = q;          // K4 writes (q dead), K5/K6 read
    float* stats= k;          // 512 floats (k dead)

    k_node_proj<<<ROWS, 64, 0, stream>>>(x, U_np, V_np, b_np, h);
    k_qkv<<<ROWS, 64, 0, stream>>>(h, U_q, V_q, U_k, V_k, U_v, V_v, q, k, v);
    k_attn<<<BB*HH*32, 256, 0, stream>>>(q, k, v, o);
    k_out_proj<<<ROWS, 64, 0, stream>>>(o, U_o, V_o, b_o, U_op, V_op, b_op, outp);
    k_bnstats<<<DD, 256, 0, stream>>>(outp, stats, gamma, beta);
    k_bnapply<<<ROWS, 256, 0, stream>>>(outp, stats, out);
}

// Round 9
// 1041.898 us; speedup vs baseline: 3.7416x; 1.2845x over previous
//
#include <hip/hip_runtime.h>

#define BB 4
#define NN 2048
#define DD 256
#define HH 8
#define RR 64
#define DHH 32
#define KSP 32
#define ROWS (BB*NN)   // 8192
#define NEG_INF (-3.0e38f)
#define SSTR 18        // score row stride (floats); 72B rows, float2-aligned
#define VSTR 36        // V row stride (floats); 144B rows, float4-aligned
#define VOFF 1152      // V buffer offset inside per-wave arena (floats)

// ---------------- K1: h = (x @ U_np) @ V_np + b_np ----------------
__global__ __launch_bounds__(64) void k_node_proj(
    const float* __restrict__ x, const float* __restrict__ U,
    const float* __restrict__ V, const float* __restrict__ bias,
    float* __restrict__ h)
{
    const int row = blockIdx.x, lane = threadIdx.x;
    __shared__ float xs[DD];
    __shared__ float ts[RR];
    const float* xr = x + (size_t)row * DD;
    { float4 t4 = ((const float4*)xr)[lane];
      xs[lane*4]=t4.x; xs[lane*4+1]=t4.y; xs[lane*4+2]=t4.z; xs[lane*4+3]=t4.w; }
    __syncthreads();
    float t = 0.f;
    for (int d = 0; d < DD; ++d) t = fmaf(xs[d], U[d*RR + lane], t);
    ts[lane] = t;
    __syncthreads();
    float a[4];
    #pragma unroll
    for (int j = 0; j < 4; ++j) a[j] = bias[lane + 64*j];
    for (int r = 0; r < RR; ++r) {
        float tv = ts[r];
        const float* Vr = V + r*DD + lane;
        #pragma unroll
        for (int j = 0; j < 4; ++j) a[j] = fmaf(tv, Vr[64*j], a[j]);
    }
    float* hr = h + (size_t)row * DD;
    #pragma unroll
    for (int j = 0; j < 4; ++j) hr[lane + 64*j] = a[j];
}

// ---------------- K2: q,k,v = lowrank(h), kept in [B,N,D] layout ----------------
__global__ __launch_bounds__(64) void k_qkv(
    const float* __restrict__ h,
    const float* __restrict__ Uq, const float* __restrict__ Vq,
    const float* __restrict__ Uk, const float* __restrict__ Vk,
    const float* __restrict__ Uv, const float* __restrict__ Vv,
    float* __restrict__ q, float* __restrict__ k, float* __restrict__ v)
{
    const int row = blockIdx.x, lane = threadIdx.x;
    __shared__ float hs[DD];
    __shared__ float tq[RR], tk[RR], tvv[RR];
    const float* hr = h + (size_t)row * DD;
    { float4 t4 = ((const float4*)hr)[lane];
      hs[lane*4]=t4.x; hs[lane*4+1]=t4.y; hs[lane*4+2]=t4.z; hs[lane*4+3]=t4.w; }
    __syncthreads();
    float aq=0.f, ak=0.f, av=0.f;
    for (int d = 0; d < DD; ++d) {
        float hv = hs[d];
        aq = fmaf(hv, Uq[d*RR + lane], aq);
        ak = fmaf(hv, Uk[d*RR + lane], ak);
        av = fmaf(hv, Uv[d*RR + lane], av);
    }
    tq[lane]=aq; tk[lane]=ak; tvv[lane]=av;
    __syncthreads();
    float oq[4], ok[4], ov[4];
    #pragma unroll
    for (int j = 0; j < 4; ++j) { oq[j]=0.f; ok[j]=0.f; ov[j]=0.f; }
    for (int r = 0; r < RR; ++r) {
        float sq=tq[r], sk=tk[r], sv=tvv[r];
        const int base = r*DD + lane;
        #pragma unroll
        for (int j = 0; j < 4; ++j) {
            oq[j] = fmaf(sq, Vq[base + 64*j], oq[j]);
            ok[j] = fmaf(sk, Vk[base + 64*j], ok[j]);
            ov[j] = fmaf(sv, Vv[base + 64*j], ov[j]);
        }
    }
    float* qr = q + (size_t)row * DD;
    float* kr = k + (size_t)row * DD;
    float* vr = v + (size_t)row * DD;
    #pragma unroll
    for (int j = 0; j < 4; ++j) {
        qr[lane + 64*j] = oq[j];
        kr[lane + 64*j] = ok[j];
        vr[lane + 64*j] = ov[j];
    }
}

// branchless exact insert into sorted-ascending 32-list (med3 identity)
#define INSERT32(tp, sm) do { \
    _Pragma("unroll") for (int _i = 0; _i < 31; ++_i) \
        (tp)[_i] = __builtin_amdgcn_fmed3f((sm), (tp)[_i], (tp)[_i+1]); \
    (tp)[31] = fmaxf((tp)[31], (sm)); \
} while (0)

// ---------------- K3: sparse top-32 attention ----------------
// 4 waves/block own the same 64 queries; wave w scans keys [512w,512w+512) in
// 32 chunks of 16. Q tile (pre-scaled) staged once in block LDS. Per chunk:
// lane=(key,dquarter) holds K quarter-row in regs (double-buffered prefetch);
// scores via dot8 + 2x shfl_xor (fixed order, identical both passes), written
// through per-wave LDS transpose; lane=query does exact med3 top-32 insert.
// 4-way merge -> exact m,thr. Pass 2 recomputes scores identically, selects
// s>=thr, PV from LDS-staged V chunk (broadcast reads). Arena reuse:
// scores -> top-lists -> scores+V -> acc partials. LDS = 40 KB -> 4 blocks/CU.
__global__ __launch_bounds__(256, 4) void k_attn(
    const float* __restrict__ qx, const float* __restrict__ kx,
    const float* __restrict__ vx, float* __restrict__ o)
{
    __shared__ float arena[4][2048];   // 32 KB per-wave arena
    __shared__ float qtile[2048];      // 8 KB Q tile [64][32]; swl after Q dies
    const int tid  = threadIdx.x;
    const int lane = tid & 63;
    const int wv   = tid >> 6;
    const int blk  = blockIdx.x;
    const int tile = blk & 31;
    const int head = (blk >> 5) & 7;
    const int b    = blk >> 8;

    const float scale = 0.17677669529663687f;  // 1/sqrt(32)

    // ---- stage Q tile (pre-scaled) once per block ----
    {
        const int row = tid >> 2, part = tid & 3;
        const float* qp = qx + (size_t)(b*NN + tile*64 + row)*DD + head*DHH + part*8;
        float4 a = ((const float4*)qp)[0];
        float4 c = ((const float4*)qp)[1];
        a.x*=scale; a.y*=scale; a.z*=scale; a.w*=scale;
        c.x*=scale; c.y*=scale; c.z*=scale; c.w*=scale;
        float* w = qtile + row*32 + part*8;
        ((float4*)w)[0] = a; ((float4*)w)[1] = c;
    }
    __syncthreads();

    const int key = lane & 15;           // key within 16-chunk
    const int qtr = lane >> 4;           // d-quarter (8 floats)
    const float* Kb = kx + (size_t)b*NN*DD + head*DHH + qtr*8;
    const float* Vb = vx + (size_t)b*NN*DD + head*DHH;
    float* sbuf = arena[wv];             // [64][SSTR]
    float* vbuf = arena[wv] + VOFF;      // [16][VSTR]
    const int j0 = wv*512;

    // scores for one 16-key chunk; EXACT same code both passes
    auto score16 = [&](const float4 k0, const float4 k1) {
        #pragma unroll 8
        for (int qi = 0; qi < 64; ++qi) {
            const float4* qp = (const float4*)(qtile + qi*32 + qtr*8);
            float4 q0 = qp[0], q1 = qp[1];
            float s0 = fmaf(q1.x, k1.x, q0.x*k0.x);
            float s1 = fmaf(q1.y, k1.y, q0.y*k0.y);
            float s2 = fmaf(q1.z, k1.z, q0.z*k0.z);
            float s3 = fmaf(q1.w, k1.w, q0.w*k0.w);
            float p = (s0+s1)+(s2+s3);
            p += __shfl_xor(p, 16, 64);
            p += __shfl_xor(p, 32, 64);
            if (lane < 16) sbuf[qi*SSTR + key] = p;
        }
    };

    // ---------------- pass 1: exact per-query top-32 ----------------
    float t[32];
    #pragma unroll
    for (int i = 0; i < 32; ++i) t[i] = NEG_INF;

    {
        float4 kA0, kA1, kB0, kB1;
        { const float4* kp = (const float4*)(Kb + (size_t)(j0 + key)*DD);
          kA0 = kp[0]; kA1 = kp[1]; }
        for (int c = 0; c < 32; c += 2) {
            { const float4* kp = (const float4*)(Kb + (size_t)(j0 + (c+1)*16 + key)*DD);
              kB0 = kp[0]; kB1 = kp[1]; }
            score16(kA0, kA1);
            #pragma unroll
            for (int i = 0; i < 8; ++i) {
                float2 sv = *(const float2*)(sbuf + lane*SSTR + 2*i);
                INSERT32(t, sv.x);
                INSERT32(t, sv.y);
            }
            if (c+2 < 32) {
                const float4* kp = (const float4*)(Kb + (size_t)(j0 + (c+2)*16 + key)*DD);
                kA0 = kp[0]; kA1 = kp[1];
            }
            score16(kB0, kB1);
            #pragma unroll
            for (int i = 0; i < 8; ++i) {
                float2 sv = *(const float2*)(sbuf + lane*SSTR + 2*i);
                INSERT32(t, sv.x);
                INSERT32(t, sv.y);
            }
        }
    }
    // publish top lists into own arena (scorebuf dead)
    #pragma unroll
    for (int i = 0; i < 32; ++i) arena[wv][i*64 + lane] = t[i];
    __syncthreads();

    // ---- merge 4 sorted lists: exact m (pick 0) and thr (pick 31) ----
    int i0=31, i1=31, i2=31, i3=31;
    float m = NEG_INF, thr = NEG_INF;
    for (int p = 0; p < 32; ++p) {
        float v0 = arena[0][i0*64 + lane];
        float v1 = arena[1][i1*64 + lane];
        float v2 = arena[2][i2*64 + lane];
        float v3 = arena[3][i3*64 + lane];
        float vm = fmaxf(fmaxf(v0,v1), fmaxf(v2,v3));
        if (p == 0) m = vm;
        thr = vm;
        if      (vm == v0) --i0;
        else if (vm == v1) --i1;
        else if (vm == v2) --i2;
        else               --i3;
    }
    __syncthreads();   // all waves done reading lists before arena reuse

    // ---------------- pass 2: recompute, select s>=thr, PV ----------------
    float acc[32];
    #pragma unroll
    for (int d = 0; d < 32; ++d) acc[d] = 0.f;
    float sw = 0.f;

    auto pv16 = [&](const float4 k0, const float4 k1,
                    const float4 vr0, const float4 vr1) {
        score16(k0, k1);
        { float* vw = vbuf + (lane>>2)*VSTR + (lane&3)*8;
          ((float4*)vw)[0] = vr0; ((float4*)vw)[1] = vr1; }
        #pragma unroll
        for (int i = 0; i < 8; ++i) {
            float2 sv = *(const float2*)(sbuf + lane*SSTR + 2*i);
            #pragma unroll
            for (int hsel = 0; hsel < 2; ++hsel) {
                float s = hsel ? sv.y : sv.x;
                int kk = 2*i + hsel;
                bool sel = (s >= thr);
                float w = sel ? __expf(s - m) : 0.f;
                sw += w;
                if (__any(sel)) {
                    const float4* vv = (const float4*)(vbuf + kk*VSTR);
                    #pragma unroll
                    for (int r = 0; r < 8; ++r) {
                        float4 vvv = vv[r];
                        acc[4*r]   = fmaf(w, vvv.x, acc[4*r]);
                        acc[4*r+1] = fmaf(w, vvv.y, acc[4*r+1]);
                        acc[4*r+2] = fmaf(w, vvv.z, acc[4*r+2]);
                        acc[4*r+3] = fmaf(w, vvv.w, acc[4*r+3]);
                    }
                }
            }
        }
    };

    {
        float4 kA0, kA1, kB0, kB1;
        { const float4* kp = (const float4*)(Kb + (size_t)(j0 + key)*DD);
          kA0 = kp[0]; kA1 = kp[1]; }
        for (int c = 0; c < 32; c += 2) {
            { const float4* kp = (const float4*)(Kb + (size_t)(j0 + (c+1)*16 + key)*DD);
              kB0 = kp[0]; kB1 = kp[1]; }
            float4 vA0, vA1;
            { const float* vp = Vb + (size_t)(j0 + c*16 + (lane>>2))*DD + (lane&3)*8;
              vA0 = ((const float4*)vp)[0]; vA1 = ((const float4*)vp)[1]; }
            pv16(kA0, kA1, vA0, vA1);
            if (c+2 < 32) {
                const float4* kp = (const float4*)(Kb + (size_t)(j0 + (c+2)*16 + key)*DD);
                kA0 = kp[0]; kA1 = kp[1];
            }
            float4 vB0, vB1;
            { const float* vp = Vb + (size_t)(j0 + (c+1)*16 + (lane>>2))*DD + (lane&3)*8;
              vB0 = ((const float4*)vp)[0]; vB1 = ((const float4*)vp)[1]; }
            pv16(kB0, kB1, vB0, vB1);
        }
    }

    // publish acc partials into own arena (sbuf/vbuf dead)
    #pragma unroll
    for (int d = 0; d < 32; ++d) arena[wv][d*64 + lane] = acc[d];
    __syncthreads();               // everyone done with Q tile + acc published
    qtile[wv*64 + lane] = sw;      // swl lives in dead Q area
    __syncthreads();

    float swsum = qtile[lane] + qtile[64+lane] + qtile[128+lane] + qtile[192+lane];
    float inv = 1.0f / swsum;
    float* orow = o + ((size_t)(b*NN + tile*64 + lane))*DD + head*DHH;
    #pragma unroll
    for (int dd = 0; dd < 8; ++dd) {
        int d = 8*wv + dd;
        float sv = arena[0][d*64+lane] + arena[1][d*64+lane]
                 + arena[2][d*64+lane] + arena[3][d*64+lane];
        orow[d] = sv * inv;
    }
}

// ---------------- K4: out_pre = lowrank(lowrank(o)) ----------------
__global__ __launch_bounds__(64) void k_out_proj(
    const float* __restrict__ o,
    const float* __restrict__ Uo,  const float* __restrict__ Vo,  const float* __restrict__ bo,
    const float* __restrict__ Uop, const float* __restrict__ Vop, const float* __restrict__ bop,
    float* __restrict__ outp)
{
    const int row = blockIdx.x, lane = threadIdx.x;
    __shared__ float buf[DD];
    __shared__ float ts[RR];
    const float* orow = o + (size_t)row * DD;
    { float4 t4 = ((const float4*)orow)[lane];
      buf[lane*4]=t4.x; buf[lane*4+1]=t4.y; buf[lane*4+2]=t4.z; buf[lane*4+3]=t4.w; }
    __syncthreads();
    float t = 0.f;
    for (int d = 0; d < DD; ++d) t = fmaf(buf[d], Uo[d*RR + lane], t);
    ts[lane] = t;
    __syncthreads();
    float a[4];
    #pragma unroll
    for (int j = 0; j < 4; ++j) a[j] = bo[lane + 64*j];
    for (int r = 0; r < RR; ++r) {
        float tv = ts[r];
        #pragma unroll
        for (int j = 0; j < 4; ++j) a[j] = fmaf(tv, Vo[r*DD + lane + 64*j], a[j]);
    }
    __syncthreads();
    #pragma unroll
    for (int j = 0; j < 4; ++j) buf[lane + 64*j] = a[j];
    __syncthreads();
    float t2 = 0.f;
    for (int d = 0; d < DD; ++d) t2 = fmaf(buf[d], Uop[d*RR + lane], t2);
    __syncthreads();
    ts[lane] = t2;
    __syncthreads();
    float c[4];
    #pragma unroll
    for (int j = 0; j < 4; ++j) c[j] = bop[lane + 64*j];
    for (int r = 0; r < RR; ++r) {
        float tv = ts[r];
        #pragma unroll
        for (int j = 0; j < 4; ++j) c[j] = fmaf(tv, Vop[r*DD + lane + 64*j], c[j]);
    }
    float* orow_out = outp + (size_t)row * DD;
    #pragma unroll
    for (int j = 0; j < 4; ++j) orow_out[lane + 64*j] = c[j];
}

// ---------------- K5: BN batch stats per channel ----------------
__global__ __launch_bounds__(256) void k_bnstats(
    const float* __restrict__ outp, float* __restrict__ stats,
    const float* __restrict__ gamma, const float* __restrict__ beta)
{
    const int c = blockIdx.x, t = threadIdx.x;
    float s = 0.f, s2 = 0.f;
    for (int r = t; r < ROWS; r += 256) {
        float v = outp[(size_t)r*DD + c];
        s += v; s2 += v*v;
    }
    __shared__ float rs[256], rs2[256];
    rs[t] = s; rs2[t] = s2;
    __syncthreads();
    for (int step = 128; step; step >>= 1) {
        if (t < step) { rs[t] += rs[t+step]; rs2[t] += rs2[t+step]; }
        __syncthreads();
    }
    if (t == 0) {
        float mean = rs[0] * (1.0f/ROWS);
        float var  = rs2[0] * (1.0f/ROWS) - mean*mean;
        float inv  = rsqrtf(var + 1e-5f);
        float g = gamma[c], be = beta[c];
        stats[c]      = g * inv;
        stats[DD + c] = be - mean * g * inv;
    }
}

// ---------------- K6: apply BN (fp32 out) ----------------
__global__ __launch_bounds__(256) void k_bnapply(
    const float* __restrict__ outp, const float* __restrict__ stats,
    float* __restrict__ out)
{
    const size_t idx = (size_t)blockIdx.x * 256 + threadIdx.x;
    const int c = (int)(idx & (DD-1));
    out[idx] = outp[idx] * stats[c] + stats[DD + c];
}

extern "C" void kernel_launch(void* const* d_in, const int* in_sizes, int n_in,
                              void* d_out, int out_size, void* d_ws, size_t ws_size,
                              hipStream_t stream)
{
    (void)in_sizes; (void)n_in; (void)out_size; (void)ws_size;
    const float* x    = (const float*)d_in[0];
    const float* U_np = (const float*)d_in[1];
    const float* V_np = (const float*)d_in[2];
    const float* b_np = (const float*)d_in[3];
    const float* U_q  = (const float*)d_in[4];
    const float* V_q  = (const float*)d_in[5];
    const float* U_k  = (const float*)d_in[6];
    const float* V_k  = (const float*)d_in[7];
    const float* U_v  = (const float*)d_in[8];
    const float* V_v  = (const float*)d_in[9];
    const float* U_o  = (const float*)d_in[10];
    const float* V_o  = (const float*)d_in[11];
    const float* b_o  = (const float*)d_in[12];
    const float* U_op = (const float*)d_in[13];
    const float* V_op = (const float*)d_in[14];
    const float* b_op = (const float*)d_in[15];
    const float* gamma= (const float*)d_in[16];
    const float* beta = (const float*)d_in[17];

    float* ws  = (float*)d_ws;
    float* out = (float*)d_out;
    const size_t BUF = (size_t)ROWS * DD;     // 2,097,152 floats = 8 MB

    float* h    = out;        // K1 writes, K2 reads, dead after
    float* q    = ws;
    float* k    = ws + BUF;
    float* v    = ws + 2*BUF;
    float* o    = out;        // K3 writes (h dead), K4 reads
    float* outp = q;          // K4 writes (q dead), K5/K6 read
    float* stats= k;          // 512 floats (k dead)

    k_node_proj<<<ROWS, 64, 0, stream>>>(x, U_np, V_np, b_np, h);
    k_qkv<<<ROWS, 64, 0, stream>>>(h, U_q, V_q, U_k, V_k, U_v, V_v, q, k, v);
    k_attn<<<BB*HH*32, 256, 0, stream>>>(q, k, v, o);
    k_out_proj<<<ROWS, 64, 0, stream>>>(o, U_o, V_o, b_o, U_op, V_op, b_op, outp);
    k_bnstats<<<DD, 256, 0, stream>>>(outp, stats, gamma, beta);
    k_bnapply<<<ROWS, 256, 0, stream>>>(outp, stats, out);
}

// Round 10
// 1036.560 us; speedup vs baseline: 3.7609x; 1.0052x over previous
//
#include <hip/hip_runtime.h>

#define BB 4
#define NN 2048
#define DD 256
#define HH 8
#define RR 64
#define DHH 32
#define KSP 32
#define ROWS (BB*NN)   // 8192
#define NEG_INF (-3.0e38f)
#define SSTR 18        // score row stride (floats); 72B rows, float2-aligned
#define VSTR 36        // V row stride (floats); 144B rows, float4-aligned
#define VOFF 1152      // V buffer offset inside per-wave arena (floats)

// ---------------- K1: h = (x @ U_np) @ V_np + b_np ----------------
__global__ __launch_bounds__(64) void k_node_proj(
    const float* __restrict__ x, const float* __restrict__ U,
    const float* __restrict__ V, const float* __restrict__ bias,
    float* __restrict__ h)
{
    const int row = blockIdx.x, lane = threadIdx.x;
    __shared__ float xs[DD];
    __shared__ float ts[RR];
    const float* xr = x + (size_t)row * DD;
    { float4 t4 = ((const float4*)xr)[lane];
      xs[lane*4]=t4.x; xs[lane*4+1]=t4.y; xs[lane*4+2]=t4.z; xs[lane*4+3]=t4.w; }
    __syncthreads();
    float t = 0.f;
    for (int d = 0; d < DD; ++d) t = fmaf(xs[d], U[d*RR + lane], t);
    ts[lane] = t;
    __syncthreads();
    float a[4];
    #pragma unroll
    for (int j = 0; j < 4; ++j) a[j] = bias[lane + 64*j];
    for (int r = 0; r < RR; ++r) {
        float tv = ts[r];
        const float* Vr = V + r*DD + lane;
        #pragma unroll
        for (int j = 0; j < 4; ++j) a[j] = fmaf(tv, Vr[64*j], a[j]);
    }
    float* hr = h + (size_t)row * DD;
    #pragma unroll
    for (int j = 0; j < 4; ++j) hr[lane + 64*j] = a[j];
}

// ---------------- K2: q,k,v = lowrank(h), kept in [B,N,D] layout ----------------
__global__ __launch_bounds__(64) void k_qkv(
    const float* __restrict__ h,
    const float* __restrict__ Uq, const float* __restrict__ Vq,
    const float* __restrict__ Uk, const float* __restrict__ Vk,
    const float* __restrict__ Uv, const float* __restrict__ Vv,
    float* __restrict__ q, float* __restrict__ k, float* __restrict__ v)
{
    const int row = blockIdx.x, lane = threadIdx.x;
    __shared__ float hs[DD];
    __shared__ float tq[RR], tk[RR], tvv[RR];
    const float* hr = h + (size_t)row * DD;
    { float4 t4 = ((const float4*)hr)[lane];
      hs[lane*4]=t4.x; hs[lane*4+1]=t4.y; hs[lane*4+2]=t4.z; hs[lane*4+3]=t4.w; }
    __syncthreads();
    float aq=0.f, ak=0.f, av=0.f;
    for (int d = 0; d < DD; ++d) {
        float hv = hs[d];
        aq = fmaf(hv, Uq[d*RR + lane], aq);
        ak = fmaf(hv, Uk[d*RR + lane], ak);
        av = fmaf(hv, Uv[d*RR + lane], av);
    }
    tq[lane]=aq; tk[lane]=ak; tvv[lane]=av;
    __syncthreads();
    float oq[4], ok[4], ov[4];
    #pragma unroll
    for (int j = 0; j < 4; ++j) { oq[j]=0.f; ok[j]=0.f; ov[j]=0.f; }
    for (int r = 0; r < RR; ++r) {
        float sq=tq[r], sk=tk[r], sv=tvv[r];
        const int base = r*DD + lane;
        #pragma unroll
        for (int j = 0; j < 4; ++j) {
            oq[j] = fmaf(sq, Vq[base + 64*j], oq[j]);
            ok[j] = fmaf(sk, Vk[base + 64*j], ok[j]);
            ov[j] = fmaf(sv, Vv[base + 64*j], ov[j]);
        }
    }
    float* qr = q + (size_t)row * DD;
    float* kr = k + (size_t)row * DD;
    float* vr = v + (size_t)row * DD;
    #pragma unroll
    for (int j = 0; j < 4; ++j) {
        qr[lane + 64*j] = oq[j];
        kr[lane + 64*j] = ok[j];
        vr[lane + 64*j] = ov[j];
    }
}

// branchless exact insert into sorted-ascending 32-list (med3 identity)
#define INSERT32(tp, sm) do { \
    _Pragma("unroll") for (int _i = 0; _i < 31; ++_i) \
        (tp)[_i] = __builtin_amdgcn_fmed3f((sm), (tp)[_i], (tp)[_i+1]); \
    (tp)[31] = fmaxf((tp)[31], (sm)); \
} while (0)

// ---------------- K3: sparse top-32 attention ----------------
// Same structure as round 9 (passing, absmax 0.0156): 4 waves/block own the same
// 64 queries; wave w scans keys [512w,512w+512) in 32 chunks of 16. Q tile
// (pre-scaled) staged once in block LDS. Per chunk: lane=(key,dquarter) holds K
// quarter-row in regs (double-buffered prefetch); scores via dot8 + 2x shfl_xor
// (fixed order, identical both passes), LDS transpose; lane=query exact med3
// top-32 insert. 4-way merge -> exact m,thr. Pass 2 recomputes identically,
// selects s>=thr, PV from LDS-staged V chunk. LDS = 40 KB -> 4 blocks/CU.
// NEW: amdgpu_waves_per_eu(4,4) — LDS caps at 4 waves/EU anyway; give the
// register allocator the full 128-VGPR budget so t[32]/K-frags stay in arch
// VGPRs (round 9's VGPR_Count=64 => AGPR banking => ~1.7x inst inflation).
__global__ __launch_bounds__(256)
__attribute__((amdgpu_waves_per_eu(4, 4)))
void k_attn(
    const float* __restrict__ qx, const float* __restrict__ kx,
    const float* __restrict__ vx, float* __restrict__ o)
{
    __shared__ float arena[4][2048];   // 32 KB per-wave arena
    __shared__ float qtile[2048];      // 8 KB Q tile [64][32]; swl after Q dies
    const int tid  = threadIdx.x;
    const int lane = tid & 63;
    const int wv   = tid >> 6;
    const int blk  = blockIdx.x;
    const int tile = blk & 31;
    const int head = (blk >> 5) & 7;
    const int b    = blk >> 8;

    const float scale = 0.17677669529663687f;  // 1/sqrt(32)

    // ---- stage Q tile (pre-scaled) once per block ----
    {
        const int row = tid >> 2, part = tid & 3;
        const float* qp = qx + (size_t)(b*NN + tile*64 + row)*DD + head*DHH + part*8;
        float4 a = ((const float4*)qp)[0];
        float4 c = ((const float4*)qp)[1];
        a.x*=scale; a.y*=scale; a.z*=scale; a.w*=scale;
        c.x*=scale; c.y*=scale; c.z*=scale; c.w*=scale;
        float* w = qtile + row*32 + part*8;
        ((float4*)w)[0] = a; ((float4*)w)[1] = c;
    }
    __syncthreads();

    const int key = lane & 15;           // key within 16-chunk
    const int qtr = lane >> 4;           // d-quarter (8 floats)
    const float* Kb = kx + (size_t)b*NN*DD + head*DHH + qtr*8;
    const float* Vb = vx + (size_t)b*NN*DD + head*DHH;
    float* sbuf = arena[wv];             // [64][SSTR]
    float* vbuf = arena[wv] + VOFF;      // [16][VSTR]
    const int j0 = wv*512;

    // per-lane base pointers, advanced by increments (no per-load addr rebuild)
    const float* kp0 = Kb + (size_t)(j0 + key)*DD;             // K row, chunk 0
    const float* vp0 = Vb + (size_t)(j0 + (lane>>2))*DD + (lane&3)*8;  // V stage
    const size_t KSTEP = (size_t)16*DD;                        // one chunk

    // scores for one 16-key chunk; EXACT same code both passes (round-9 order)
    auto score16 = [&](const float4 k0, const float4 k1) {
        #pragma unroll 16
        for (int qi = 0; qi < 64; ++qi) {
            const float4* qp = (const float4*)(qtile + qi*32 + qtr*8);
            float4 q0 = qp[0], q1 = qp[1];
            float s0 = fmaf(q1.x, k1.x, q0.x*k0.x);
            float s1 = fmaf(q1.y, k1.y, q0.y*k0.y);
            float s2 = fmaf(q1.z, k1.z, q0.z*k0.z);
            float s3 = fmaf(q1.w, k1.w, q0.w*k0.w);
            float p = (s0+s1)+(s2+s3);
            p += __shfl_xor(p, 16, 64);
            p += __shfl_xor(p, 32, 64);
            if (lane < 16) sbuf[qi*SSTR + key] = p;
        }
    };

    // ---------------- pass 1: exact per-query top-32 ----------------
    float t[32];
    #pragma unroll
    for (int i = 0; i < 32; ++i) t[i] = NEG_INF;

    {
        const float* kc = kp0;
        float4 kA0, kA1, kB0, kB1;
        { const float4* kp = (const float4*)kc;
          kA0 = kp[0]; kA1 = kp[1]; }
        for (int c = 0; c < 32; c += 2) {
            { const float4* kp = (const float4*)(kc + KSTEP);
              kB0 = kp[0]; kB1 = kp[1]; }
            score16(kA0, kA1);
            #pragma unroll
            for (int i = 0; i < 8; ++i) {
                float2 sv = *(const float2*)(sbuf + lane*SSTR + 2*i);
                INSERT32(t, sv.x);
                INSERT32(t, sv.y);
            }
            if (c+2 < 32) {
                const float4* kp = (const float4*)(kc + 2*KSTEP);
                kA0 = kp[0]; kA1 = kp[1];
            }
            score16(kB0, kB1);
            #pragma unroll
            for (int i = 0; i < 8; ++i) {
                float2 sv = *(const float2*)(sbuf + lane*SSTR + 2*i);
                INSERT32(t, sv.x);
                INSERT32(t, sv.y);
            }
            kc += 2*KSTEP;
        }
    }
    // publish top lists into own arena (scorebuf dead)
    #pragma unroll
    for (int i = 0; i < 32; ++i) arena[wv][i*64 + lane] = t[i];
    __syncthreads();

    // ---- merge 4 sorted lists: exact m (pick 0) and thr (pick 31) ----
    int i0=31, i1=31, i2=31, i3=31;
    float m = NEG_INF, thr = NEG_INF;
    for (int p = 0; p < 32; ++p) {
        float v0 = arena[0][i0*64 + lane];
        float v1 = arena[1][i1*64 + lane];
        float v2 = arena[2][i2*64 + lane];
        float v3 = arena[3][i3*64 + lane];
        float vm = fmaxf(fmaxf(v0,v1), fmaxf(v2,v3));
        if (p == 0) m = vm;
        thr = vm;
        if      (vm == v0) --i0;
        else if (vm == v1) --i1;
        else if (vm == v2) --i2;
        else               --i3;
    }
    __syncthreads();   // all waves done reading lists before arena reuse

    // ---------------- pass 2: recompute, select s>=thr, PV ----------------
    float acc[32];
    #pragma unroll
    for (int d = 0; d < 32; ++d) acc[d] = 0.f;
    float sw = 0.f;

    auto pv16 = [&](const float4 k0, const float4 k1,
                    const float4 vr0, const float4 vr1) {
        score16(k0, k1);
        { float* vw = vbuf + (lane>>2)*VSTR + (lane&3)*8;
          ((float4*)vw)[0] = vr0; ((float4*)vw)[1] = vr1; }
        #pragma unroll
        for (int i = 0; i < 8; ++i) {
            float2 sv = *(const float2*)(sbuf + lane*SSTR + 2*i);
            #pragma unroll
            for (int hsel = 0; hsel < 2; ++hsel) {
                float s = hsel ? sv.y : sv.x;
                int kk = 2*i + hsel;
                bool sel = (s >= thr);
                float w = sel ? __expf(s - m) : 0.f;
                sw += w;
                if (__any(sel)) {
                    const float4* vv = (const float4*)(vbuf + kk*VSTR);
                    #pragma unroll
                    for (int r = 0; r < 8; ++r) {
                        float4 vvv = vv[r];
                        acc[4*r]   = fmaf(w, vvv.x, acc[4*r]);
                        acc[4*r+1] = fmaf(w, vvv.y, acc[4*r+1]);
                        acc[4*r+2] = fmaf(w, vvv.z, acc[4*r+2]);
                        acc[4*r+3] = fmaf(w, vvv.w, acc[4*r+3]);
                    }
                }
            }
        }
    };

    {
        const float* kc = kp0;
        const float* vc = vp0;
        float4 kA0, kA1, kB0, kB1;
        { const float4* kp = (const float4*)kc;
          kA0 = kp[0]; kA1 = kp[1]; }
        for (int c = 0; c < 32; c += 2) {
            { const float4* kp = (const float4*)(kc + KSTEP);
              kB0 = kp[0]; kB1 = kp[1]; }
            float4 vA0, vA1;
            { vA0 = ((const float4*)vc)[0]; vA1 = ((const float4*)vc)[1]; }
            pv16(kA0, kA1, vA0, vA1);
            if (c+2 < 32) {
                const float4* kp = (const float4*)(kc + 2*KSTEP);
                kA0 = kp[0]; kA1 = kp[1];
            }
            float4 vB0, vB1;
            { const float* vp = vc + KSTEP;
              vB0 = ((const float4*)vp)[0]; vB1 = ((const float4*)vp)[1]; }
            pv16(kB0, kB1, vB0, vB1);
            kc += 2*KSTEP;
            vc += 2*KSTEP;
        }
    }

    // publish acc partials into own arena (sbuf/vbuf dead)
    #pragma unroll
    for (int d = 0; d < 32; ++d) arena[wv][d*64 + lane] = acc[d];
    __syncthreads();               // everyone done with Q tile + acc published
    qtile[wv*64 + lane] = sw;      // swl lives in dead Q area
    __syncthreads();

    float swsum = qtile[lane] + qtile[64+lane] + qtile[128+lane] + qtile[192+lane];
    float inv = 1.0f / swsum;
    float* orow = o + ((size_t)(b*NN + tile*64 + lane))*DD + head*DHH;
    #pragma unroll
    for (int dd = 0; dd < 8; ++dd) {
        int d = 8*wv + dd;
        float sv = arena[0][d*64+lane] + arena[1][d*64+lane]
                 + arena[2][d*64+lane] + arena[3][d*64+lane];
        orow[d] = sv * inv;
    }
}

// ---------------- K4: out_pre = lowrank(lowrank(o)) ----------------
__global__ __launch_bounds__(64) void k_out_proj(
    const float* __restrict__ o,
    const float* __restrict__ Uo,  const float* __restrict__ Vo,  const float* __restrict__ bo,
    const float* __restrict__ Uop, const float* __restrict__ Vop, const float* __restrict__ bop,
    float* __restrict__ outp)
{
    const int row = blockIdx.x, lane = threadIdx.x;
    __shared__ float buf[DD];
    __shared__ float ts[RR];
    const float* orow = o + (size_t)row * DD;
    { float4 t4 = ((const float4*)orow)[lane];
      buf[lane*4]=t4.x; buf[lane*4+1]=t4.y; buf[lane*4+2]=t4.z; buf[lane*4+3]=t4.w; }
    __syncthreads();
    float t = 0.f;
    for (int d = 0; d < DD; ++d) t = fmaf(buf[d], Uo[d*RR + lane], t);
    ts[lane] = t;
    __syncthreads();
    float a[4];
    #pragma unroll
    for (int j = 0; j < 4; ++j) a[j] = bo[lane + 64*j];
    for (int r = 0; r < RR; ++r) {
        float tv = ts[r];
        #pragma unroll
        for (int j = 0; j < 4; ++j) a[j] = fmaf(tv, Vo[r*DD + lane + 64*j], a[j]);
    }
    __syncthreads();
    #pragma unroll
    for (int j = 0; j < 4; ++j) buf[lane + 64*j] = a[j];
    __syncthreads();
    float t2 = 0.f;
    for (int d = 0; d < DD; ++d) t2 = fmaf(buf[d], Uop[d*RR + lane], t2);
    __syncthreads();
    ts[lane] = t2;
    __syncthreads();
    float c[4];
    #pragma unroll
    for (int j = 0; j < 4; ++j) c[j] = bop[lane + 64*j];
    for (int r = 0; r < RR; ++r) {
        float tv = ts[r];
        #pragma unroll
        for (int j = 0; j < 4; ++j) c[j] = fmaf(tv, Vop[r*DD + lane + 64*j], c[j]);
    }
    float* orow_out = outp + (size_t)row * DD;
    #pragma unroll
    for (int j = 0; j < 4; ++j) orow_out[lane + 64*j] = c[j];
}

// ---------------- K5: BN batch stats per channel ----------------
__global__ __launch_bounds__(256) void k_bnstats(
    const float* __restrict__ outp, float* __restrict__ stats,
    const float* __restrict__ gamma, const float* __restrict__ beta)
{
    const int c = blockIdx.x, t = threadIdx.x;
    float s = 0.f, s2 = 0.f;
    for (int r = t; r < ROWS; r += 256) {
        float v = outp[(size_t)r*DD + c];
        s += v; s2 += v*v;
    }
    __shared__ float rs[256], rs2[256];
    rs[t] = s; rs2[t] = s2;
    __syncthreads();
    for (int step = 128; step; step >>= 1) {
        if (t < step) { rs[t] += rs[t+step]; rs2[t] += rs2[t+step]; }
        __syncthreads();
    }
    if (t == 0) {
        float mean = rs[0] * (1.0f/ROWS);
        float var  = rs2[0] * (1.0f/ROWS) - mean*mean;
        float inv  = rsqrtf(var + 1e-5f);
        float g = gamma[c], be = beta[c];
        stats[c]      = g * inv;
        stats[DD + c] = be - mean * g * inv;
    }
}

// ---------------- K6: apply BN (fp32 out) ----------------
__global__ __launch_bounds__(256) void k_bnapply(
    const float* __restrict__ outp, const float* __restrict__ stats,
    float* __restrict__ out)
{
    const size_t idx = (size_t)blockIdx.x * 256 + threadIdx.x;
    const int c = (int)(idx & (DD-1));
    out[idx] = outp[idx] * stats[c] + stats[DD + c];
}

extern "C" void kernel_launch(void* const* d_in, const int* in_sizes, int n_in,
                              void* d_out, int out_size, void* d_ws, size_t ws_size,
                              hipStream_t stream)
{
    (void)in_sizes; (void)n_in; (void)out_size; (void)ws_size;
    const float* x    = (const float*)d_in[0];
    const float* U_np = (const float*)d_in[1];
    const float* V_np = (const float*)d_in[2];
    const float* b_np = (const float*)d_in[3];
    const float* U_q  = (const float*)d_in[4];
    const float* V_q  = (const float*)d_in[5];
    const float* U_k  = (const float*)d_in[6];
    const float* V_k  = (const float*)d_in[7];
    const float* U_v  = (const float*)d_in[8];
    const float* V_v  = (const float*)d_in[9];
    const float* U_o  = (const float*)d_in[10];
    const float* V_o  = (const float*)d_in[11];
    const float* b_o  = (const float*)d_in[12];
    const float* U_op = (const float*)d_in[13];
    const float* V_op = (const float*)d_in[14];
    const float* b_op = (const float*)d_in[15];
    const float* gamma= (const float*)d_in[16];
    const float* beta = (const float*)d_in[17];

    float* ws  = (float*)d_ws;
    float* out = (float*)d_out;
    const size_t BUF = (size_t)ROWS * DD;     // 2,097,152 floats = 8 MB

    float* h    = out;        // K1 writes, K2 reads, dead after
    float* q    = ws;
    float* k    = ws + BUF;
    float* v    = ws + 2*BUF;
    float* o    = out;        // K3 writes (h dead), K4 reads
    float* outp = q;          // K4 writes (q dead), K5/K6 read
    float* stats= k;          // 512 floats (k dead)

    k_node_proj<<<ROWS, 64, 0, stream>>>(x, U_np, V_np, b_np, h);
    k_qkv<<<ROWS, 64, 0, stream>>>(h, U_q, V_q, U_k, V_k, U_v, V_v, q, k, v);
    k_attn<<<BB*HH*32, 256, 0, stream>>>(q, k, v, o);
    k_out_proj<<<ROWS, 64, 0, stream>>>(o, U_o, V_o, b_o, U_op, V_op, b_op, outp);
    k_bnstats<<<DD, 256, 0, stream>>>(outp, stats, gamma, beta);
    k_bnapply<<<ROWS, 256, 0, stream>>>(outp, stats, out);
}

// Round 11
// 744.206 us; speedup vs baseline: 5.2384x; 1.3928x over previous
//
#include <hip/hip_runtime.h>

#define BB 4
#define NN 2048
#define DD 256
#define HH 8
#define RR 64
#define DHH 32
#define KSP 32
#define ROWS (BB*NN)   // 8192
#define NEG_INF (-3.0e38f)
#define KST 36         // LDS row stride (floats): 144B, 16B-aligned, 2-way bank alias only
#define SLOT 576       // 16 rows * KST floats per ring slot

// ---------------- K1: h = (x @ U_np) @ V_np + b_np ----------------
__global__ __launch_bounds__(64) void k_node_proj(
    const float* __restrict__ x, const float* __restrict__ U,
    const float* __restrict__ V, const float* __restrict__ bias,
    float* __restrict__ h)
{
    const int row = blockIdx.x, lane = threadIdx.x;
    __shared__ float xs[DD];
    __shared__ float ts[RR];
    const float* xr = x + (size_t)row * DD;
    { float4 t4 = ((const float4*)xr)[lane];
      xs[lane*4]=t4.x; xs[lane*4+1]=t4.y; xs[lane*4+2]=t4.z; xs[lane*4+3]=t4.w; }
    __syncthreads();
    float t = 0.f;
    for (int d = 0; d < DD; ++d) t = fmaf(xs[d], U[d*RR + lane], t);
    ts[lane] = t;
    __syncthreads();
    float a[4];
    #pragma unroll
    for (int j = 0; j < 4; ++j) a[j] = bias[lane + 64*j];
    for (int r = 0; r < RR; ++r) {
        float tv = ts[r];
        const float* Vr = V + r*DD + lane;
        #pragma unroll
        for (int j = 0; j < 4; ++j) a[j] = fmaf(tv, Vr[64*j], a[j]);
    }
    float* hr = h + (size_t)row * DD;
    #pragma unroll
    for (int j = 0; j < 4; ++j) hr[lane + 64*j] = a[j];
}

// ---------------- K2: q,k,v = lowrank(h), kept in [B,N,D] layout ----------------
__global__ __launch_bounds__(64) void k_qkv(
    const float* __restrict__ h,
    const float* __restrict__ Uq, const float* __restrict__ Vq,
    const float* __restrict__ Uk, const float* __restrict__ Vk,
    const float* __restrict__ Uv, const float* __restrict__ Vv,
    float* __restrict__ q, float* __restrict__ k, float* __restrict__ v)
{
    const int row = blockIdx.x, lane = threadIdx.x;
    __shared__ float hs[DD];
    __shared__ float tq[RR], tk[RR], tvv[RR];
    const float* hr = h + (size_t)row * DD;
    { float4 t4 = ((const float4*)hr)[lane];
      hs[lane*4]=t4.x; hs[lane*4+1]=t4.y; hs[lane*4+2]=t4.z; hs[lane*4+3]=t4.w; }
    __syncthreads();
    float aq=0.f, ak=0.f, av=0.f;
    for (int d = 0; d < DD; ++d) {
        float hv = hs[d];
        aq = fmaf(hv, Uq[d*RR + lane], aq);
        ak = fmaf(hv, Uk[d*RR + lane], ak);
        av = fmaf(hv, Uv[d*RR + lane], av);
    }
    tq[lane]=aq; tk[lane]=ak; tvv[lane]=av;
    __syncthreads();
    float oq[4], ok[4], ov[4];
    #pragma unroll
    for (int j = 0; j < 4; ++j) { oq[j]=0.f; ok[j]=0.f; ov[j]=0.f; }
    for (int r = 0; r < RR; ++r) {
        float sq=tq[r], sk=tk[r], sv=tvv[r];
        const int base = r*DD + lane;
        #pragma unroll
        for (int j = 0; j < 4; ++j) {
            oq[j] = fmaf(sq, Vq[base + 64*j], oq[j]);
            ok[j] = fmaf(sk, Vk[base + 64*j], ok[j]);
            ov[j] = fmaf(sv, Vv[base + 64*j], ov[j]);
        }
    }
    float* qr = q + (size_t)row * DD;
    float* kr = k + (size_t)row * DD;
    float* vr = v + (size_t)row * DD;
    #pragma unroll
    for (int j = 0; j < 4; ++j) {
        qr[lane + 64*j] = oq[j];
        kr[lane + 64*j] = ok[j];
        vr[lane + 64*j] = ov[j];
    }
}

// branchless exact insert into sorted-ascending 32-list (med3 identity)
#define INSERT32(tp, sm) do { \
    _Pragma("unroll") for (int _i = 0; _i < 31; ++_i) \
        (tp)[_i] = __builtin_amdgcn_fmed3f((sm), (tp)[_i], (tp)[_i+1]); \
    (tp)[31] = fmaxf((tp)[31], (sm)); \
} while (0)

// cooperative 16-key chunk staging (issue global->regs / write regs->LDS)
// lane -> row = lane>>2 (16 rows), colgroup = lane&3 (8 floats each)
#define STAGE_ISSUE(a0_, a1_, base, firstkey) do { \
    const float* _p = (base) + (size_t)((firstkey) + (lane>>2))*DD + (lane&3)*8; \
    (a0_) = ((const float4*)_p)[0]; (a1_) = ((const float4*)_p)[1]; \
} while (0)
#define STAGE_WRITE(slot, a0_, a1_) do { \
    float* _w = (slot) + (lane>>2)*KST + (lane&3)*8; \
    ((float4*)_w)[0] = (a0_); ((float4*)_w)[1] = (a1_); \
} while (0)

// ---------------- K3: sparse top-32 attention, lane = query, Q-in-regs ----------------
// 4 waves/block own the same 64 queries (lane = query, Q row in 8xfloat4 regs,
// pre-scaled). Wave w scans keys [512w,512w+512) in 32 chunks of 16, staged into
// a per-wave LDS ring (issue-early/write-late). Each key row is read as a
// wave-uniform LDS broadcast; every lane computes its own full 32-FMA dot -> no
// shfl, no score transpose. Exact med3 top-32 insert per key. 4-way merge gives
// exact m (max) and thr (32nd); pass 2 recomputes s with the IDENTICAL dot
// helper, selects s>=thr (exact tie semantics), PV from LDS-broadcast V rows.
__global__ __launch_bounds__(256)
__attribute__((amdgpu_waves_per_eu(4, 4)))
void k_attn(
    const float* __restrict__ qx, const float* __restrict__ kx,
    const float* __restrict__ vx, float* __restrict__ o)
{
    __shared__ float arena[4][4*SLOT];   // 36.9 KB: ring / top-lists / acc
    __shared__ float swl[256];           // 1 KB
    const int tid  = threadIdx.x;
    const int lane = tid & 63;
    const int wv   = tid >> 6;
    const int blk  = blockIdx.x;
    const int tile = blk & 31;
    const int head = (blk >> 5) & 7;
    const int b    = blk >> 8;

    const float scale = 0.17677669529663687f;  // 1/sqrt(32)

    const float* Kb = kx + (size_t)b*NN*DD + head*DHH;
    const float* Vb = vx + (size_t)b*NN*DD + head*DHH;
    float* aw = arena[wv];
    const int j0 = wv*512;

    // ---- Q row into registers (pre-scaled), one query per lane ----
    float4 qreg[8];
    {
        const float* qp = qx + ((size_t)(b*NN + tile*64 + lane))*DD + head*DHH;
        #pragma unroll
        for (int i = 0; i < 8; ++i) {
            float4 t4 = ((const float4*)qp)[i];
            t4.x*=scale; t4.y*=scale; t4.z*=scale; t4.w*=scale;
            qreg[i] = t4;
        }
    }

    // identical dot in both passes: 4 partial sums over broadcast K row
    auto dotK = [&](const float* kr) -> float {
        float s0=0.f, s1=0.f, s2=0.f, s3=0.f;
        #pragma unroll
        for (int i = 0; i < 8; ++i) {
            float4 kv = ((const float4*)kr)[i];   // wave-uniform broadcast
            s0 = fmaf(qreg[i].x, kv.x, s0);
            s1 = fmaf(qreg[i].y, kv.y, s1);
            s2 = fmaf(qreg[i].z, kv.z, s2);
            s3 = fmaf(qreg[i].w, kv.w, s3);
        }
        return (s0+s1)+(s2+s3);
    };

    // ---------------- pass 1: exact per-query top-32 ----------------
    float t[32];
    #pragma unroll
    for (int i = 0; i < 32; ++i) t[i] = NEG_INF;

    {
        float4 a0, a1;
        STAGE_ISSUE(a0, a1, Kb, j0);          // chunk 0
        STAGE_WRITE(aw, a0, a1);
        STAGE_ISSUE(a0, a1, Kb, j0 + 16);     // chunk 1 in flight
        for (int c = 0; c < 32; ++c) {
            float* cur = aw + (c & 1)*SLOT;
            if (c >= 1) STAGE_WRITE(cur, a0, a1);            // write chunk c
            if (c + 1 < 32) STAGE_ISSUE(a0, a1, Kb, j0 + (c+1)*16);
            #pragma unroll 2
            for (int kk = 0; kk < 16; ++kk) {
                float s = dotK(cur + kk*KST);
                INSERT32(t, s);
            }
        }
    }
    // publish top lists (ring dead)
    #pragma unroll
    for (int i = 0; i < 32; ++i) aw[i*64 + lane] = t[i];
    __syncthreads();

    // ---- merge 4 sorted lists: exact m (pick 0) and thr (pick 31) ----
    int i0=31, i1=31, i2=31, i3=31;
    float m = NEG_INF, thr = NEG_INF;
    for (int p = 0; p < 32; ++p) {
        float v0 = arena[0][i0*64 + lane];
        float v1 = arena[1][i1*64 + lane];
        float v2 = arena[2][i2*64 + lane];
        float v3 = arena[3][i3*64 + lane];
        float vm = fmaxf(fmaxf(v0,v1), fmaxf(v2,v3));
        if (p == 0) m = vm;
        thr = vm;
        if      (vm == v0) --i0;
        else if (vm == v1) --i1;
        else if (vm == v2) --i2;
        else               --i3;
    }
    __syncthreads();   // all waves done reading lists before ring reuse

    // ---------------- pass 2: recompute, select s>=thr, PV ----------------
    float acc[32];
    #pragma unroll
    for (int d = 0; d < 32; ++d) acc[d] = 0.f;
    float sw = 0.f;

    {
        // K slots {0,1}, V slots {2,3}
        float4 ka0, ka1, va0, va1;
        STAGE_ISSUE(ka0, ka1, Kb, j0);
        STAGE_ISSUE(va0, va1, Vb, j0);
        STAGE_WRITE(aw,          ka0, ka1);
        STAGE_WRITE(aw + 2*SLOT, va0, va1);
        STAGE_ISSUE(ka0, ka1, Kb, j0 + 16);
        STAGE_ISSUE(va0, va1, Vb, j0 + 16);
        for (int c = 0; c < 32; ++c) {
            float* kcur = aw + (c & 1)*SLOT;
            float* vcur = aw + (2 + (c & 1))*SLOT;
            if (c >= 1) {
                STAGE_WRITE(kcur, ka0, ka1);
                STAGE_WRITE(vcur, va0, va1);
            }
            if (c + 1 < 32) {
                STAGE_ISSUE(ka0, ka1, Kb, j0 + (c+1)*16);
                STAGE_ISSUE(va0, va1, Vb, j0 + (c+1)*16);
            }
            #pragma unroll 2
            for (int kk = 0; kk < 16; ++kk) {
                float s = dotK(kcur + kk*KST);
                bool sel = (s >= thr);
                float w = sel ? __expf(s - m) : 0.f;
                sw += w;
                if (__any(sel)) {
                    const float* vr = vcur + kk*KST;
                    #pragma unroll
                    for (int i = 0; i < 8; ++i) {
                        float4 vv = ((const float4*)vr)[i];   // broadcast
                        acc[4*i]   = fmaf(w, vv.x, acc[4*i]);
                        acc[4*i+1] = fmaf(w, vv.y, acc[4*i+1]);
                        acc[4*i+2] = fmaf(w, vv.z, acc[4*i+2]);
                        acc[4*i+3] = fmaf(w, vv.w, acc[4*i+3]);
                    }
                }
            }
        }
    }

    // publish acc partials into own arena (ring dead)
    #pragma unroll
    for (int d = 0; d < 32; ++d) aw[d*64 + lane] = acc[d];
    swl[wv*64 + lane] = sw;
    __syncthreads();

    float swsum = swl[lane] + swl[64+lane] + swl[128+lane] + swl[192+lane];
    float inv = 1.0f / swsum;
    float* orow = o + ((size_t)(b*NN + tile*64 + lane))*DD + head*DHH;
    #pragma unroll
    for (int dd = 0; dd < 8; ++dd) {
        int d = 8*wv + dd;
        float sv = arena[0][d*64+lane] + arena[1][d*64+lane]
                 + arena[2][d*64+lane] + arena[3][d*64+lane];
        orow[d] = sv * inv;
    }
}

// ---------------- K4: out_pre = lowrank(lowrank(o)) ----------------
__global__ __launch_bounds__(64) void k_out_proj(
    const float* __restrict__ o,
    const float* __restrict__ Uo,  const float* __restrict__ Vo,  const float* __restrict__ bo,
    const float* __restrict__ Uop, const float* __restrict__ Vop, const float* __restrict__ bop,
    float* __restrict__ outp)
{
    const int row = blockIdx.x, lane = threadIdx.x;
    __shared__ float buf[DD];
    __shared__ float ts[RR];
    const float* orow = o + (size_t)row * DD;
    { float4 t4 = ((const float4*)orow)[lane];
      buf[lane*4]=t4.x; buf[lane*4+1]=t4.y; buf[lane*4+2]=t4.z; buf[lane*4+3]=t4.w; }
    __syncthreads();
    float t = 0.f;
    for (int d = 0; d < DD; ++d) t = fmaf(buf[d], Uo[d*RR + lane], t);
    ts[lane] = t;
    __syncthreads();
    float a[4];
    #pragma unroll
    for (int j = 0; j < 4; ++j) a[j] = bo[lane + 64*j];
    for (int r = 0; r < RR; ++r) {
        float tv = ts[r];
        #pragma unroll
        for (int j = 0; j < 4; ++j) a[j] = fmaf(tv, Vo[r*DD + lane + 64*j], a[j]);
    }
    __syncthreads();
    #pragma unroll
    for (int j = 0; j < 4; ++j) buf[lane + 64*j] = a[j];
    __syncthreads();
    float t2 = 0.f;
    for (int d = 0; d < DD; ++d) t2 = fmaf(buf[d], Uop[d*RR + lane], t2);
    __syncthreads();
    ts[lane] = t2;
    __syncthreads();
    float c[4];
    #pragma unroll
    for (int j = 0; j < 4; ++j) c[j] = bop[lane + 64*j];
    for (int r = 0; r < RR; ++r) {
        float tv = ts[r];
        #pragma unroll
        for (int j = 0; j < 4; ++j) c[j] = fmaf(tv, Vop[r*DD + lane + 64*j], c[j]);
    }
    float* orow_out = outp + (size_t)row * DD;
    #pragma unroll
    for (int j = 0; j < 4; ++j) orow_out[lane + 64*j] = c[j];
}

// ---------------- K5: BN batch stats per channel ----------------
__global__ __launch_bounds__(256) void k_bnstats(
    const float* __restrict__ outp, float* __restrict__ stats,
    const float* __restrict__ gamma, const float* __restrict__ beta)
{
    const int c = blockIdx.x, t = threadIdx.x;
    float s = 0.f, s2 = 0.f;
    for (int r = t; r < ROWS; r += 256) {
        float v = outp[(size_t)r*DD + c];
        s += v; s2 += v*v;
    }
    __shared__ float rs[256], rs2[256];
    rs[t] = s; rs2[t] = s2;
    __syncthreads();
    for (int step = 128; step; step >>= 1) {
        if (t < step) { rs[t] += rs[t+step]; rs2[t] += rs2[t+step]; }
        __syncthreads();
    }
    if (t == 0) {
        float mean = rs[0] * (1.0f/ROWS);
        float var  = rs2[0] * (1.0f/ROWS) - mean*mean;
        float inv  = rsqrtf(var + 1e-5f);
        float g = gamma[c], be = beta[c];
        stats[c]      = g * inv;
        stats[DD + c] = be - mean * g * inv;
    }
}

// ---------------- K6: apply BN (fp32 out) ----------------
__global__ __launch_bounds__(256) void k_bnapply(
    const float* __restrict__ outp, const float* __restrict__ stats,
    float* __restrict__ out)
{
    const size_t idx = (size_t)blockIdx.x * 256 + threadIdx.x;
    const int c = (int)(idx & (DD-1));
    out[idx] = outp[idx] * stats[c] + stats[DD + c];
}

extern "C" void kernel_launch(void* const* d_in, const int* in_sizes, int n_in,
                              void* d_out, int out_size, void* d_ws, size_t ws_size,
                              hipStream_t stream)
{
    (void)in_sizes; (void)n_in; (void)out_size; (void)ws_size;
    const float* x    = (const float*)d_in[0];
    const float* U_np = (const float*)d_in[1];
    const float* V_np = (const float*)d_in[2];
    const float* b_np = (const float*)d_in[3];
    const float* U_q  = (const float*)d_in[4];
    const float* V_q  = (const float*)d_in[5];
    const float* U_k  = (const float*)d_in[6];
    const float* V_k  = (const float*)d_in[7];
    const float* U_v  = (const float*)d_in[8];
    const float* V_v  = (const float*)d_in[9];
    const float* U_o  = (const float*)d_in[10];
    const float* V_o  = (const float*)d_in[11];
    const float* b_o  = (const float*)d_in[12];
    const float* U_op = (const float*)d_in[13];
    const float* V_op = (const float*)d_in[14];
    const float* b_op = (const float*)d_in[15];
    const float* gamma= (const float*)d_in[16];
    const float* beta = (const float*)d_in[17];

    float* ws  = (float*)d_ws;
    float* out = (float*)d_out;
    const size_t BUF = (size_t)ROWS * DD;     // 2,097,152 floats = 8 MB

    float* h    = out;        // K1 writes, K2 reads, dead after
    float* q    = ws;
    float* k    = ws + BUF;
    float* v    = ws + 2*BUF;
    float* o    = out;        // K3 writes (h dead), K4 reads
    float* outp = q;          // K4 writes (q dead), K5/K6 read
    float* stats= k;          // 512 floats (k dead)

    k_node_proj<<<ROWS, 64, 0, stream>>>(x, U_np, V_np, b_np, h);
    k_qkv<<<ROWS, 64, 0, stream>>>(h, U_q, V_q, U_k, V_k, U_v, V_v, q, k, v);
    k_attn<<<BB*HH*32, 256, 0, stream>>>(q, k, v, o);
    k_out_proj<<<ROWS, 64, 0, stream>>>(o, U_o, V_o, b_o, U_op, V_op, b_op, outp);
    k_bnstats<<<DD, 256, 0, stream>>>(outp, stats, gamma, beta);
    k_bnapply<<<ROWS, 256, 0, stream>>>(outp, stats, out);
}

// Round 12
// 531.785 us; speedup vs baseline: 7.3308x; 1.3994x over previous
//
#include <hip/hip_runtime.h>
#include <hip/hip_bf16.h>

#define BB 4
#define NN 2048
#define DD 256
#define HH 8
#define RR 64
#define DHH 32
#define KSP 32
#define ROWS (BB*NN)   // 8192
#define NEG_INF (-3.0e38f)

typedef __attribute__((ext_vector_type(8))) short bf16x8;
typedef __attribute__((ext_vector_type(4))) float f32x4;
#define MFMA16(A,B,C) __builtin_amdgcn_mfma_f32_16x16x32_bf16((A),(B),(C),0,0,0)

// ---------------- K1: h = (x @ U_np) @ V_np + b_np ----------------
__global__ __launch_bounds__(64) void k_node_proj(
    const float* __restrict__ x, const float* __restrict__ U,
    const float* __restrict__ V, const float* __restrict__ bias,
    float* __restrict__ h)
{
    const int row = blockIdx.x, lane = threadIdx.x;
    __shared__ float xs[DD];
    __shared__ float ts[RR];
    const float* xr = x + (size_t)row * DD;
    { float4 t4 = ((const float4*)xr)[lane];
      xs[lane*4]=t4.x; xs[lane*4+1]=t4.y; xs[lane*4+2]=t4.z; xs[lane*4+3]=t4.w; }
    __syncthreads();
    float t = 0.f;
    for (int d = 0; d < DD; ++d) t = fmaf(xs[d], U[d*RR + lane], t);
    ts[lane] = t;
    __syncthreads();
    float a[4];
    #pragma unroll
    for (int j = 0; j < 4; ++j) a[j] = bias[lane + 64*j];
    for (int r = 0; r < RR; ++r) {
        float tv = ts[r];
        const float* Vr = V + r*DD + lane;
        #pragma unroll
        for (int j = 0; j < 4; ++j) a[j] = fmaf(tv, Vr[64*j], a[j]);
    }
    float* hr = h + (size_t)row * DD;
    #pragma unroll
    for (int j = 0; j < 4; ++j) hr[lane + 64*j] = a[j];
}

// ---------------- K2: q,k,v = lowrank(h), kept in [B,N,D] layout ----------------
__global__ __launch_bounds__(64) void k_qkv(
    const float* __restrict__ h,
    const float* __restrict__ Uq, const float* __restrict__ Vq,
    const float* __restrict__ Uk, const float* __restrict__ Vk,
    const float* __restrict__ Uv, const float* __restrict__ Vv,
    float* __restrict__ q, float* __restrict__ k, float* __restrict__ v)
{
    const int row = blockIdx.x, lane = threadIdx.x;
    __shared__ float hs[DD];
    __shared__ float tq[RR], tk[RR], tvv[RR];
    const float* hr = h + (size_t)row * DD;
    { float4 t4 = ((const float4*)hr)[lane];
      hs[lane*4]=t4.x; hs[lane*4+1]=t4.y; hs[lane*4+2]=t4.z; hs[lane*4+3]=t4.w; }
    __syncthreads();
    float aq=0.f, ak=0.f, av=0.f;
    for (int d = 0; d < DD; ++d) {
        float hv = hs[d];
        aq = fmaf(hv, Uq[d*RR + lane], aq);
        ak = fmaf(hv, Uk[d*RR + lane], ak);
        av = fmaf(hv, Uv[d*RR + lane], av);
    }
    tq[lane]=aq; tk[lane]=ak; tvv[lane]=av;
    __syncthreads();
    float oq[4], ok[4], ov[4];
    #pragma unroll
    for (int j = 0; j < 4; ++j) { oq[j]=0.f; ok[j]=0.f; ov[j]=0.f; }
    for (int r = 0; r < RR; ++r) {
        float sq=tq[r], sk=tk[r], sv=tvv[r];
        const int base = r*DD + lane;
        #pragma unroll
        for (int j = 0; j < 4; ++j) {
            oq[j] = fmaf(sq, Vq[base + 64*j], oq[j]);
            ok[j] = fmaf(sk, Vk[base + 64*j], ok[j]);
            ov[j] = fmaf(sv, Vv[base + 64*j], ov[j]);
        }
    }
    float* qr = q + (size_t)row * DD;
    float* kr = k + (size_t)row * DD;
    float* vr = v + (size_t)row * DD;
    #pragma unroll
    for (int j = 0; j < 4; ++j) {
        qr[lane + 64*j] = oq[j];
        kr[lane + 64*j] = ok[j];
        vr[lane + 64*j] = ov[j];
    }
}

// branchless exact insert into sorted-ascending 32-list (med3 identity)
#define INSERT32(tp, sm) do { \
    _Pragma("unroll") for (int _i = 0; _i < 31; ++_i) \
        (tp)[_i] = __builtin_amdgcn_fmed3f((sm), (tp)[_i], (tp)[_i+1]); \
    (tp)[31] = fmaxf((tp)[31], (sm)); \
} while (0)

__device__ __forceinline__ unsigned short f2bf(float x) {
    __hip_bfloat16 h = __float2bfloat16(x);
    return *reinterpret_cast<unsigned short*>(&h);
}
__device__ __forceinline__ float bf2f(unsigned short u) {
    __hip_bfloat16 h; *reinterpret_cast<unsigned short*>(&h) = u;
    return __bfloat162float(h);
}
// 3-way bf16 split: x = b1 + b2 + b3 + O(2^-27 x)
__device__ __forceinline__ void split3(float x, unsigned short& b1,
                                       unsigned short& b2, unsigned short& b3) {
    b1 = f2bf(x);        float f1 = bf2f(b1);
    float r = x - f1;    b2 = f2bf(r);
    float f2 = bf2f(b2); float r2 = r - f2;
    b3 = f2bf(r2);
}

// ---------------- K3: sparse top-32 attention, MFMA bf16x3 scores ----------------
// Round-11 skeleton (lane=query, exact med3 top-32, 4-way merge, broadcast PV)
// with the score dot moved to the matrix pipe: S = Q*K^T via 6-term bf16x3
// MFMA (error ~1e-7, fp32-class; identical chain in both passes so selection
// semantics are exact). Per chunk of 16 keys: K staged as 3 bf16 planes in LDS
// (issue-early/write-late), B-fragments ds_read_b128, 4 q-tiles x 6 MFMA,
// C written through an LDS transpose, lane=query reads its 16 scores.
__global__ __launch_bounds__(256)
__attribute__((amdgpu_waves_per_eu(3, 3)))
void k_attn(
    const float* __restrict__ qx, const float* __restrict__ kx,
    const float* __restrict__ vx, float* __restrict__ o)
{
    __shared__ float arena[4][2688];   // per-wave: kbuf(960) sc(1152) vbuf(576)
    __shared__ float swl[256];
    const int tid  = threadIdx.x;
    const int lane = tid & 63;
    const int wv   = tid >> 6;
    const int blk  = blockIdx.x;
    const int tile = blk & 31;
    const int head = (blk >> 5) & 7;
    const int b    = blk >> 8;
    const float scale = 0.17677669529663687f;  // 1/sqrt(32)

    float* aw  = arena[wv];
    unsigned int* kbu = (unsigned int*)aw;   // [3][16][20] uints (bf16 pairs)
    float* scW = aw + 960;                   // [64][18] scores
    float* vbW = aw + 2112;                  // [16][36] V chunk

    const float* Kb = kx + (size_t)b*NN*DD + head*DHH;
    const float* Vb = vx + (size_t)b*NN*DD + head*DHH;
    const int j0 = wv*512;

    // ---- A fragments: Q tiles (scaled), 3-way bf16 split, in registers ----
    bf16x8 aq[4][3];
    {
        const int qr = lane & 15, ko = (lane >> 4) * 8;
        const float* qbase = qx + ((size_t)(b*NN + tile*64))*DD + head*DHH + ko;
        #pragma unroll
        for (int t = 0; t < 4; ++t) {
            const float* qp = qbase + (size_t)(t*16 + qr)*DD;
            float4 x0 = ((const float4*)qp)[0];
            float4 x1 = ((const float4*)qp)[1];
            float xv[8] = {x0.x,x0.y,x0.z,x0.w,x1.x,x1.y,x1.z,x1.w};
            #pragma unroll
            for (int i = 0; i < 8; ++i) {
                unsigned short u1,u2,u3;
                split3(xv[i]*scale, u1, u2, u3);
                aq[t][0][i] = (short)u1;
                aq[t][1][i] = (short)u2;
                aq[t][2][i] = (short)u3;
            }
        }
    }

    // staging role: lane -> (key = lane>>2, grp = lane&3 covering 8 dims)
    const int skey = lane >> 2, sgrp = lane & 3;
    const float* kSrc = Kb + (size_t)skey*DD + sgrp*8;
    const float* vSrc = Vb + (size_t)skey*DD + sgrp*8;

    // convert 8 raw K floats -> 3 bf16 planes, write 16B per plane
    auto convwrite_k = [&](float4 f0, float4 f1) {
        float xv[8] = {f0.x,f0.y,f0.z,f0.w,f1.x,f1.y,f1.z,f1.w};
        unsigned int w1[4], w2[4], w3[4];
        #pragma unroll
        for (int i = 0; i < 4; ++i) {
            unsigned short a0,b0,c0,a1,b1,c1;
            split3(xv[2*i],   a0, b0, c0);
            split3(xv[2*i+1], a1, b1, c1);
            w1[i] = (unsigned int)a0 | ((unsigned int)a1 << 16);
            w2[i] = (unsigned int)b0 | ((unsigned int)b1 << 16);
            w3[i] = (unsigned int)c0 | ((unsigned int)c1 << 16);
        }
        *(uint4*)(kbu + ( 0 + skey)*20 + sgrp*4) = make_uint4(w1[0],w1[1],w1[2],w1[3]);
        *(uint4*)(kbu + (16 + skey)*20 + sgrp*4) = make_uint4(w2[0],w2[1],w2[2],w2[3]);
        *(uint4*)(kbu + (32 + skey)*20 + sgrp*4) = make_uint4(w3[0],w3[1],w3[2],w3[3]);
    };

    // scores for chunk in kbuf -> scW[64][18]; IDENTICAL both passes
    auto scores_chunk = [&]() {
        const unsigned short* kb16 = (const unsigned short*)kbu;
        const int key = lane & 15, ko = (lane >> 4) * 8;
        bf16x8 bk0 = *(const bf16x8*)(kb16 + ( 0 + key)*40 + ko);
        bf16x8 bk1 = *(const bf16x8*)(kb16 + (16 + key)*40 + ko);
        bf16x8 bk2 = *(const bf16x8*)(kb16 + (32 + key)*40 + ko);
        const int qr0 = (lane >> 4) * 4;
        #pragma unroll
        for (int t = 0; t < 4; ++t) {
            f32x4 c4 = {0.f, 0.f, 0.f, 0.f};
            c4 = MFMA16(aq[t][0], bk0, c4);   // q1k1
            c4 = MFMA16(aq[t][0], bk1, c4);   // q1k2
            c4 = MFMA16(aq[t][1], bk0, c4);   // q2k1
            c4 = MFMA16(aq[t][0], bk2, c4);   // q1k3
            c4 = MFMA16(aq[t][2], bk0, c4);   // q3k1
            c4 = MFMA16(aq[t][1], bk1, c4);   // q2k2
            #pragma unroll
            for (int r = 0; r < 4; ++r)
                scW[(t*16 + qr0 + r)*18 + key] = c4[r];
        }
    };

    // ---------------- pass 1: exact per-query top-32 ----------------
    float t32[32];
    #pragma unroll
    for (int i = 0; i < 32; ++i) t32[i] = NEG_INF;

    {
        float4 k0, k1;
        { const float* p = kSrc + (size_t)j0*DD;
          k0 = ((const float4*)p)[0]; k1 = ((const float4*)p)[1]; }
        convwrite_k(k0, k1);
        for (int c = 0; c < 32; ++c) {
            if (c + 1 < 32) {
                const float* p = kSrc + (size_t)(j0 + (c+1)*16)*DD;
                k0 = ((const float4*)p)[0]; k1 = ((const float4*)p)[1];
            }
            scores_chunk();
            const float2* sp = (const float2*)(scW + lane*18);
            #pragma unroll
            for (int i = 0; i < 8; ++i) {
                float2 s2 = sp[i];
                INSERT32(t32, s2.x);
                INSERT32(t32, s2.y);
            }
            if (c + 1 < 32) convwrite_k(k0, k1);
        }
    }
    #pragma unroll
    for (int i = 0; i < 32; ++i) aw[i*64 + lane] = t32[i];
    __syncthreads();

    // ---- merge 4 sorted lists: exact m (pick 0) and thr (pick 31) ----
    int i0=31, i1=31, i2=31, i3=31;
    float m = NEG_INF, thr = NEG_INF;
    for (int p = 0; p < 32; ++p) {
        float v0 = arena[0][i0*64 + lane];
        float v1 = arena[1][i1*64 + lane];
        float v2 = arena[2][i2*64 + lane];
        float v3 = arena[3][i3*64 + lane];
        float vm = fmaxf(fmaxf(v0,v1), fmaxf(v2,v3));
        if (p == 0) m = vm;
        thr = vm;
        if      (vm == v0) --i0;
        else if (vm == v1) --i1;
        else if (vm == v2) --i2;
        else               --i3;
    }
    __syncthreads();   // all waves done reading lists before arena reuse

    // ---------------- pass 2: recompute (identical), select s>=thr, PV ------
    float acc[32];
    #pragma unroll
    for (int d = 0; d < 32; ++d) acc[d] = 0.f;
    float sw = 0.f;

    {
        float4 k0, k1, v0, v1;
        { const float* p = kSrc + (size_t)j0*DD;
          k0 = ((const float4*)p)[0]; k1 = ((const float4*)p)[1]; }
        { const float* p = vSrc + (size_t)j0*DD;
          v0 = ((const float4*)p)[0]; v1 = ((const float4*)p)[1]; }
        convwrite_k(k0, k1);
        { float* wp = vbW + skey*36 + sgrp*8;
          *(float4*)wp = v0; *(float4*)(wp + 4) = v1; }
        for (int c = 0; c < 32; ++c) {
            if (c + 1 < 32) {
                const float* p = kSrc + (size_t)(j0 + (c+1)*16)*DD;
                k0 = ((const float4*)p)[0]; k1 = ((const float4*)p)[1];
                const float* pv = vSrc + (size_t)(j0 + (c+1)*16)*DD;
                v0 = ((const float4*)pv)[0]; v1 = ((const float4*)pv)[1];
            }
            scores_chunk();
            const float2* sp = (const float2*)(scW + lane*18);
            #pragma unroll
            for (int i = 0; i < 8; ++i) {
                float2 s2 = sp[i];
                #pragma unroll
                for (int hs = 0; hs < 2; ++hs) {
                    float s = hs ? s2.y : s2.x;
                    int kk = 2*i + hs;
                    bool sel = (s >= thr);
                    float w = sel ? __expf(s - m) : 0.f;
                    sw += w;
                    if (__any(sel)) {
                        const float4* vv = (const float4*)(vbW + kk*36);
                        #pragma unroll
                        for (int r = 0; r < 8; ++r) {
                            float4 vvv = vv[r];
                            acc[4*r]   = fmaf(w, vvv.x, acc[4*r]);
                            acc[4*r+1] = fmaf(w, vvv.y, acc[4*r+1]);
                            acc[4*r+2] = fmaf(w, vvv.z, acc[4*r+2]);
                            acc[4*r+3] = fmaf(w, vvv.w, acc[4*r+3]);
                        }
                    }
                }
            }
            if (c + 1 < 32) {
                convwrite_k(k0, k1);
                float* wp = vbW + skey*36 + sgrp*8;
                *(float4*)wp = v0; *(float4*)(wp + 4) = v1;
            }
        }
    }

    // publish acc partials into own arena (kbuf/sc dead)
    #pragma unroll
    for (int d = 0; d < 32; ++d) aw[d*64 + lane] = acc[d];
    swl[wv*64 + lane] = sw;
    __syncthreads();

    float swsum = swl[lane] + swl[64+lane] + swl[128+lane] + swl[192+lane];
    float inv = 1.0f / swsum;
    float* orow = o + ((size_t)(b*NN + tile*64 + lane))*DD + head*DHH;
    #pragma unroll
    for (int dd = 0; dd < 8; ++dd) {
        int d = 8*wv + dd;
        float sv = arena[0][d*64+lane] + arena[1][d*64+lane]
                 + arena[2][d*64+lane] + arena[3][d*64+lane];
        orow[d] = sv * inv;
    }
}

// ---------------- K4: out_pre = lowrank(lowrank(o)) ----------------
__global__ __launch_bounds__(64) void k_out_proj(
    const float* __restrict__ o,
    const float* __restrict__ Uo,  const float* __restrict__ Vo,  const float* __restrict__ bo,
    const float* __restrict__ Uop, const float* __restrict__ Vop, const float* __restrict__ bop,
    float* __restrict__ outp)
{
    const int row = blockIdx.x, lane = threadIdx.x;
    __shared__ float buf[DD];
    __shared__ float ts[RR];
    const float* orow = o + (size_t)row * DD;
    { float4 t4 = ((const float4*)orow)[lane];
      buf[lane*4]=t4.x; buf[lane*4+1]=t4.y; buf[lane*4+2]=t4.z; buf[lane*4+3]=t4.w; }
    __syncthreads();
    float t = 0.f;
    for (int d = 0; d < DD; ++d) t = fmaf(buf[d], Uo[d*RR + lane], t);
    ts[lane] = t;
    __syncthreads();
    float a[4];
    #pragma unroll
    for (int j = 0; j < 4; ++j) a[j] = bo[lane + 64*j];
    for (int r = 0; r < RR; ++r) {
        float tv = ts[r];
        #pragma unroll
        for (int j = 0; j < 4; ++j) a[j] = fmaf(tv, Vo[r*DD + lane + 64*j], a[j]);
    }
    __syncthreads();
    #pragma unroll
    for (int j = 0; j < 4; ++j) buf[lane + 64*j] = a[j];
    __syncthreads();
    float t2 = 0.f;
    for (int d = 0; d < DD; ++d) t2 = fmaf(buf[d], Uop[d*RR + lane], t2);
    __syncthreads();
    ts[lane] = t2;
    __syncthreads();
    float c[4];
    #pragma unroll
    for (int j = 0; j < 4; ++j) c[j] = bop[lane + 64*j];
    for (int r = 0; r < RR; ++r) {
        float tv = ts[r];
        #pragma unroll
        for (int j = 0; j < 4; ++j) c[j] = fmaf(tv, Vop[r*DD + lane + 64*j], c[j]);
    }
    float* orow_out = outp + (size_t)row * DD;
    #pragma unroll
    for (int j = 0; j < 4; ++j) orow_out[lane + 64*j] = c[j];
}

// ---------------- K5: BN batch stats per channel ----------------
__global__ __launch_bounds__(256) void k_bnstats(
    const float* __restrict__ outp, float* __restrict__ stats,
    const float* __restrict__ gamma, const float* __restrict__ beta)
{
    const int c = blockIdx.x, t = threadIdx.x;
    float s = 0.f, s2 = 0.f;
    for (int r = t; r < ROWS; r += 256) {
        float v = outp[(size_t)r*DD + c];
        s += v; s2 += v*v;
    }
    __shared__ float rs[256], rs2[256];
    rs[t] = s; rs2[t] = s2;
    __syncthreads();
    for (int step = 128; step; step >>= 1) {
        if (t < step) { rs[t] += rs[t+step]; rs2[t] += rs2[t+step]; }
        __syncthreads();
    }
    if (t == 0) {
        float mean = rs[0] * (1.0f/ROWS);
        float var  = rs2[0] * (1.0f/ROWS) - mean*mean;
        float inv  = rsqrtf(var + 1e-5f);
        float g = gamma[c], be = beta[c];
        stats[c]      = g * inv;
        stats[DD + c] = be - mean * g * inv;
    }
}

// ---------------- K6: apply BN (fp32 out) ----------------
__global__ __launch_bounds__(256) void k_bnapply(
    const float* __restrict__ outp, const float* __restrict__ stats,
    float* __restrict__ out)
{
    const size_t idx = (size_t)blockIdx.x * 256 + threadIdx.x;
    const int c = (int)(idx & (DD-1));
    out[idx] = outp[idx] * stats[c] + stats[DD + c];
}

extern "C" void kernel_launch(void* const* d_in, const int* in_sizes, int n_in,
                              void* d_out, int out_size, void* d_ws, size_t ws_size,
                              hipStream_t stream)
{
    (void)in_sizes; (void)n_in; (void)out_size; (void)ws_size;
    const float* x    = (const float*)d_in[0];
    const float* U_np = (const float*)d_in[1];
    const float* V_np = (const float*)d_in[2];
    const float* b_np = (const float*)d_in[3];
    const float* U_q  = (const float*)d_in[4];
    const float* V_q  = (const float*)d_in[5];
    const float* U_k  = (const float*)d_in[6];
    const float* V_k  = (const float*)d_in[7];
    const float* U_v  = (const float*)d_in[8];
    const float* V_v  = (const float*)d_in[9];
    const float* U_o  = (const float*)d_in[10];
    const float* V_o  = (const float*)d_in[11];
    const float* b_o  = (const float*)d_in[12];
    const float* U_op = (const float*)d_in[13];
    const float* V_op = (const float*)d_in[14];
    const float* b_op = (const float*)d_in[15];
    const float* gamma= (const float*)d_in[16];
    const float* beta = (const float*)d_in[17];

    float* ws  = (float*)d_ws;
    float* out = (float*)d_out;
    const size_t BUF = (size_t)ROWS * DD;     // 2,097,152 floats = 8 MB

    float* h    = out;        // K1 writes, K2 reads, dead after
    float* q    = ws;
    float* k    = ws + BUF;
    float* v    = ws + 2*BUF;
    float* o    = out;        // K3 writes (h dead), K4 reads
    float* outp = q;          // K4 writes (q dead), K5/K6 read
    float* stats= k;          // 512 floats (k dead)

    k_node_proj<<<ROWS, 64, 0, stream>>>(x, U_np, V_np, b_np, h);
    k_qkv<<<ROWS, 64, 0, stream>>>(h, U_q, V_q, U_k, V_k, U_v, V_v, q, k, v);
    k_attn<<<BB*HH*32, 256, 0, stream>>>(q, k, v, o);
    k_out_proj<<<ROWS, 64, 0, stream>>>(o, U_o, V_o, b_o, U_op, V_op, b_op, outp);
    k_bnstats<<<DD, 256, 0, stream>>>(outp, stats, gamma, beta);
    k_bnapply<<<ROWS, 256, 0, stream>>>(outp, stats, out);
}

// Round 13
// 512.030 us; speedup vs baseline: 7.6137x; 1.0386x over previous
//
#include <hip/hip_runtime.h>
#include <hip/hip_bf16.h>

#define BB 4
#define NN 2048
#define DD 256
#define HH 8
#define RR 64
#define DHH 32
#define KSP 32
#define ROWS (BB*NN)   // 8192
#define NEG_INF (-3.0e38f)

typedef __attribute__((ext_vector_type(8))) short bf16x8;
typedef __attribute__((ext_vector_type(4))) float f32x4;
#define MFMA16(A,B,C) __builtin_amdgcn_mfma_f32_16x16x32_bf16((A),(B),(C),0,0,0)

// ---------------- K1: h = (x @ U_np) @ V_np + b_np ----------------
__global__ __launch_bounds__(64) void k_node_proj(
    const float* __restrict__ x, const float* __restrict__ U,
    const float* __restrict__ V, const float* __restrict__ bias,
    float* __restrict__ h)
{
    const int row = blockIdx.x, lane = threadIdx.x;
    __shared__ float xs[DD];
    __shared__ float ts[RR];
    const float* xr = x + (size_t)row * DD;
    { float4 t4 = ((const float4*)xr)[lane];
      xs[lane*4]=t4.x; xs[lane*4+1]=t4.y; xs[lane*4+2]=t4.z; xs[lane*4+3]=t4.w; }
    __syncthreads();
    float t = 0.f;
    for (int d = 0; d < DD; ++d) t = fmaf(xs[d], U[d*RR + lane], t);
    ts[lane] = t;
    __syncthreads();
    float a[4];
    #pragma unroll
    for (int j = 0; j < 4; ++j) a[j] = bias[lane + 64*j];
    for (int r = 0; r < RR; ++r) {
        float tv = ts[r];
        const float* Vr = V + r*DD + lane;
        #pragma unroll
        for (int j = 0; j < 4; ++j) a[j] = fmaf(tv, Vr[64*j], a[j]);
    }
    float* hr = h + (size_t)row * DD;
    #pragma unroll
    for (int j = 0; j < 4; ++j) hr[lane + 64*j] = a[j];
}

// ---------------- K2: q,k,v = lowrank(h), kept in [B,N,D] layout ----------------
__global__ __launch_bounds__(64) void k_qkv(
    const float* __restrict__ h,
    const float* __restrict__ Uq, const float* __restrict__ Vq,
    const float* __restrict__ Uk, const float* __restrict__ Vk,
    const float* __restrict__ Uv, const float* __restrict__ Vv,
    float* __restrict__ q, float* __restrict__ k, float* __restrict__ v)
{
    const int row = blockIdx.x, lane = threadIdx.x;
    __shared__ float hs[DD];
    __shared__ float tq[RR], tk[RR], tvv[RR];
    const float* hr = h + (size_t)row * DD;
    { float4 t4 = ((const float4*)hr)[lane];
      hs[lane*4]=t4.x; hs[lane*4+1]=t4.y; hs[lane*4+2]=t4.z; hs[lane*4+3]=t4.w; }
    __syncthreads();
    float aq=0.f, ak=0.f, av=0.f;
    for (int d = 0; d < DD; ++d) {
        float hv = hs[d];
        aq = fmaf(hv, Uq[d*RR + lane], aq);
        ak = fmaf(hv, Uk[d*RR + lane], ak);
        av = fmaf(hv, Uv[d*RR + lane], av);
    }
    tq[lane]=aq; tk[lane]=ak; tvv[lane]=av;
    __syncthreads();
    float oq[4], ok[4], ov[4];
    #pragma unroll
    for (int j = 0; j < 4; ++j) { oq[j]=0.f; ok[j]=0.f; ov[j]=0.f; }
    for (int r = 0; r < RR; ++r) {
        float sq=tq[r], sk=tk[r], sv=tvv[r];
        const int base = r*DD + lane;
        #pragma unroll
        for (int j = 0; j < 4; ++j) {
            oq[j] = fmaf(sq, Vq[base + 64*j], oq[j]);
            ok[j] = fmaf(sk, Vk[base + 64*j], ok[j]);
            ov[j] = fmaf(sv, Vv[base + 64*j], ov[j]);
        }
    }
    float* qr = q + (size_t)row * DD;
    float* kr = k + (size_t)row * DD;
    float* vr = v + (size_t)row * DD;
    #pragma unroll
    for (int j = 0; j < 4; ++j) {
        qr[lane + 64*j] = oq[j];
        kr[lane + 64*j] = ok[j];
        vr[lane + 64*j] = ov[j];
    }
}

__device__ __forceinline__ unsigned short f2bf(float x) {
    __hip_bfloat16 h = __float2bfloat16(x);
    return *reinterpret_cast<unsigned short*>(&h);
}
__device__ __forceinline__ float bf2f(unsigned short u) {
    __hip_bfloat16 h; *reinterpret_cast<unsigned short*>(&h) = u;
    return __bfloat162float(h);
}
// 3-way bf16 split: x = b1 + b2 + b3 + O(2^-27 x)
__device__ __forceinline__ void split3(float x, unsigned short& b1,
                                       unsigned short& b2, unsigned short& b3) {
    b1 = f2bf(x);        float f1 = bf2f(b1);
    float r = x - f1;    b2 = f2bf(r);
    float f2 = bf2f(b2); float r2 = r - f2;
    b3 = f2bf(r2);
}

// compare-exchange (ascending)
#define CEX(a_, b_) { float _l = fminf(a_, b_); (b_) = fmaxf(a_, b_); (a_) = _l; }

// ---------------- K3: sparse top-32 attention, MFMA bf16x3 scores ----------------
// Round-12 structure with: (a) scW aliased over kbuf (per-wave in-order DS makes
// it safe: B-frags are in regs before score writes) -> LDS 33 KB, 4 blocks/CU;
// (b) batch-bitonic top-32 merge (multiset-exact; Batcher sort16 63CE + pairing
// lemma + bitonic re-merge = 366 ops vs 512); (c) waves_per_eu(4,4).
__global__ __launch_bounds__(256)
__attribute__((amdgpu_waves_per_eu(4, 4)))
void k_attn(
    const float* __restrict__ qx, const float* __restrict__ kx,
    const float* __restrict__ vx, float* __restrict__ o)
{
    __shared__ float arena[4][2048];   // per-wave: kbuf(960)&scW(1152) aliased @0; vbW @1152; publish 2048
    __shared__ float swl[256];
    const int tid  = threadIdx.x;
    const int lane = tid & 63;
    const int wv   = tid >> 6;
    const int blk  = blockIdx.x;
    const int tile = blk & 31;
    const int head = (blk >> 5) & 7;
    const int b    = blk >> 8;
    const float scale = 0.17677669529663687f;  // 1/sqrt(32)

    float* aw  = arena[wv];
    unsigned int* kbu = (unsigned int*)aw;   // [3][16][20] uints (bf16 pairs) — aliased with scW
    float* scW = aw;                         // [64][18] scores — SAME region (in-order DS)
    float* vbW = aw + 1152;                  // [16][36] V chunk

    const float* Kb = kx + (size_t)b*NN*DD + head*DHH;
    const float* Vb = vx + (size_t)b*NN*DD + head*DHH;
    const int j0 = wv*512;

    // ---- A fragments: Q tiles (scaled), 3-way bf16 split, in registers ----
    bf16x8 aq[4][3];
    {
        const int qr = lane & 15, ko = (lane >> 4) * 8;
        const float* qbase = qx + ((size_t)(b*NN + tile*64))*DD + head*DHH + ko;
        #pragma unroll
        for (int t = 0; t < 4; ++t) {
            const float* qp = qbase + (size_t)(t*16 + qr)*DD;
            float4 x0 = ((const float4*)qp)[0];
            float4 x1 = ((const float4*)qp)[1];
            float xv[8] = {x0.x,x0.y,x0.z,x0.w,x1.x,x1.y,x1.z,x1.w};
            #pragma unroll
            for (int i = 0; i < 8; ++i) {
                unsigned short u1,u2,u3;
                split3(xv[i]*scale, u1, u2, u3);
                aq[t][0][i] = (short)u1;
                aq[t][1][i] = (short)u2;
                aq[t][2][i] = (short)u3;
            }
        }
    }

    // staging role: lane -> (key = lane>>2, grp = lane&3 covering 8 dims)
    const int skey = lane >> 2, sgrp = lane & 3;
    const float* kSrc = Kb + (size_t)skey*DD + sgrp*8;
    const float* vSrc = Vb + (size_t)skey*DD + sgrp*8;

    auto convwrite_k = [&](float4 f0, float4 f1) {
        float xv[8] = {f0.x,f0.y,f0.z,f0.w,f1.x,f1.y,f1.z,f1.w};
        unsigned int w1[4], w2[4], w3[4];
        #pragma unroll
        for (int i = 0; i < 4; ++i) {
            unsigned short a0,b0,c0,a1,b1,c1;
            split3(xv[2*i],   a0, b0, c0);
            split3(xv[2*i+1], a1, b1, c1);
            w1[i] = (unsigned int)a0 | ((unsigned int)a1 << 16);
            w2[i] = (unsigned int)b0 | ((unsigned int)b1 << 16);
            w3[i] = (unsigned int)c0 | ((unsigned int)c1 << 16);
        }
        *(uint4*)(kbu + ( 0 + skey)*20 + sgrp*4) = make_uint4(w1[0],w1[1],w1[2],w1[3]);
        *(uint4*)(kbu + (16 + skey)*20 + sgrp*4) = make_uint4(w2[0],w2[1],w2[2],w2[3]);
        *(uint4*)(kbu + (32 + skey)*20 + sgrp*4) = make_uint4(w3[0],w3[1],w3[2],w3[3]);
    };

    // scores for chunk in kbuf -> scW[64][18]; IDENTICAL both passes.
    // NOTE: all 3 B-frag reads complete (program order) before scW writes,
    // so the kbuf/scW alias is safe for a single wave's in-order DS stream.
    auto scores_chunk = [&]() {
        const unsigned short* kb16 = (const unsigned short*)kbu;
        const int key = lane & 15, ko = (lane >> 4) * 8;
        bf16x8 bk0 = *(const bf16x8*)(kb16 + ( 0 + key)*40 + ko);
        bf16x8 bk1 = *(const bf16x8*)(kb16 + (16 + key)*40 + ko);
        bf16x8 bk2 = *(const bf16x8*)(kb16 + (32 + key)*40 + ko);
        const int qr0 = (lane >> 4) * 4;
        #pragma unroll
        for (int t = 0; t < 4; ++t) {
            f32x4 c4 = {0.f, 0.f, 0.f, 0.f};
            c4 = MFMA16(aq[t][0], bk0, c4);   // q1k1
            c4 = MFMA16(aq[t][0], bk1, c4);   // q1k2
            c4 = MFMA16(aq[t][1], bk0, c4);   // q2k1
            c4 = MFMA16(aq[t][0], bk2, c4);   // q1k3
            c4 = MFMA16(aq[t][2], bk0, c4);   // q3k1
            c4 = MFMA16(aq[t][1], bk1, c4);   // q2k2
            #pragma unroll
            for (int r = 0; r < 4; ++r)
                scW[(t*16 + qr0 + r)*18 + key] = c4[r];
        }
    };

    // ---- exact batch merge of 16 new scores into sorted-asc t32[32] ----
    // 1) Batcher OEMS-16 asc (63 CE, verified vs generator)
    // 2) pairing lemma: u[i]=max(t[i], s[15-i]) keeps exactly top-32 multiset
    // 3) u bitonic->asc (32 CE); half-cleaner vs reversed t[16..31] (16 CE);
    //    strides 8..1 (64 CE) -> t sorted ascending again.
    auto merge_batch = [&](float* t, float* sb) {
        #pragma unroll
        for (int i = 0; i < 8; ++i) CEX(sb[2*i], sb[2*i+1]);
        #pragma unroll
        for (int g = 0; g < 4; ++g) { CEX(sb[4*g], sb[4*g+2]); CEX(sb[4*g+1], sb[4*g+3]); }
        #pragma unroll
        for (int g = 0; g < 4; ++g) CEX(sb[4*g+1], sb[4*g+2]);
        #pragma unroll
        for (int g = 0; g < 2; ++g) {
            CEX(sb[8*g],   sb[8*g+4]); CEX(sb[8*g+1], sb[8*g+5]);
            CEX(sb[8*g+2], sb[8*g+6]); CEX(sb[8*g+3], sb[8*g+7]);
        }
        #pragma unroll
        for (int g = 0; g < 2; ++g) { CEX(sb[8*g+2], sb[8*g+4]); CEX(sb[8*g+3], sb[8*g+5]); }
        #pragma unroll
        for (int g = 0; g < 2; ++g) {
            CEX(sb[8*g+1], sb[8*g+2]); CEX(sb[8*g+3], sb[8*g+4]); CEX(sb[8*g+5], sb[8*g+6]);
        }
        #pragma unroll
        for (int i = 0; i < 8; ++i) CEX(sb[i], sb[i+8]);
        #pragma unroll
        for (int i = 0; i < 4; ++i) CEX(sb[i+4], sb[i+8]);
        #pragma unroll
        for (int g = 0; g < 3; ++g) { CEX(sb[4*g+2], sb[4*g+4]); CEX(sb[4*g+3], sb[4*g+5]); }
        #pragma unroll
        for (int i = 0; i < 7; ++i) CEX(sb[2*i+1], sb[2*i+2]);
        // pairing (drop the 16 provably-out elements)
        float u[16];
        #pragma unroll
        for (int i = 0; i < 16; ++i) u[i] = fmaxf(t[i], sb[15-i]);
        // u is bitonic -> ascending
        #pragma unroll
        for (int st = 8; st >= 1; st >>= 1)
            #pragma unroll
            for (int i = 0; i < 16; ++i)
                if ((i & st) == 0) CEX(u[i], u[i+st]);
        // half-cleaner of [u asc | t_hi desc] (in place, disjoint index quads)
        #pragma unroll
        for (int i = 0; i < 8; ++i) {
            float hi1 = t[31-i], hi2 = t[16+i];
            float u1 = u[i],     u2 = u[15-i];
            t[i]    = fminf(u1, hi1);
            t[31-i] = fmaxf(u1, hi1);
            t[15-i] = fminf(u2, hi2);
            t[16+i] = fmaxf(u2, hi2);
        }
        #pragma unroll
        for (int st = 8; st >= 1; st >>= 1)
            #pragma unroll
            for (int i = 0; i < 32; ++i)
                if ((i & st) == 0) CEX(t[i], t[i+st]);
    };

    // ---------------- pass 1: exact per-query top-32 ----------------
    float t32[32];
    #pragma unroll
    for (int i = 0; i < 32; ++i) t32[i] = NEG_INF;

    {
        float4 k0, k1;
        { const float* p = kSrc + (size_t)j0*DD;
          k0 = ((const float4*)p)[0]; k1 = ((const float4*)p)[1]; }
        convwrite_k(k0, k1);
        for (int c = 0; c < 32; ++c) {
            if (c + 1 < 32) {
                const float* p = kSrc + (size_t)(j0 + (c+1)*16)*DD;
                k0 = ((const float4*)p)[0]; k1 = ((const float4*)p)[1];
            }
            scores_chunk();
            {
                const float2* sp = (const float2*)(scW + lane*18);
                float sb[16];
                #pragma unroll
                for (int i = 0; i < 8; ++i) { float2 v2 = sp[i]; sb[2*i] = v2.x; sb[2*i+1] = v2.y; }
                merge_batch(t32, sb);
            }
            if (c + 1 < 32) convwrite_k(k0, k1);
        }
    }
    #pragma unroll
    for (int i = 0; i < 32; ++i) aw[i*64 + lane] = t32[i];
    __syncthreads();

    // ---- merge 4 sorted lists: exact m (pick 0) and thr (pick 31) ----
    int i0=31, i1=31, i2=31, i3=31;
    float m = NEG_INF, thr = NEG_INF;
    for (int p = 0; p < 32; ++p) {
        float v0 = arena[0][i0*64 + lane];
        float v1 = arena[1][i1*64 + lane];
        float v2 = arena[2][i2*64 + lane];
        float v3 = arena[3][i3*64 + lane];
        float vm = fmaxf(fmaxf(v0,v1), fmaxf(v2,v3));
        if (p == 0) m = vm;
        thr = vm;
        if      (vm == v0) --i0;
        else if (vm == v1) --i1;
        else if (vm == v2) --i2;
        else               --i3;
    }
    __syncthreads();   // all waves done reading lists before arena reuse

    // ---------------- pass 2: recompute (identical), select s>=thr, PV ------
    float acc[32];
    #pragma unroll
    for (int d = 0; d < 32; ++d) acc[d] = 0.f;
    float sw = 0.f;

    {
        float4 k0, k1, v0, v1;
        { const float* p = kSrc + (size_t)j0*DD;
          k0 = ((const float4*)p)[0]; k1 = ((const float4*)p)[1]; }
        { const float* p = vSrc + (size_t)j0*DD;
          v0 = ((const float4*)p)[0]; v1 = ((const float4*)p)[1]; }
        convwrite_k(k0, k1);
        { float* wp = vbW + skey*36 + sgrp*8;
          *(float4*)wp = v0; *(float4*)(wp + 4) = v1; }
        for (int c = 0; c < 32; ++c) {
            if (c + 1 < 32) {
                const float* p = kSrc + (size_t)(j0 + (c+1)*16)*DD;
                k0 = ((const float4*)p)[0]; k1 = ((const float4*)p)[1];
                const float* pv = vSrc + (size_t)(j0 + (c+1)*16)*DD;
                v0 = ((const float4*)pv)[0]; v1 = ((const float4*)pv)[1];
            }
            scores_chunk();
            const float2* sp = (const float2*)(scW + lane*18);
            #pragma unroll
            for (int i = 0; i < 8; ++i) {
                float2 s2 = sp[i];
                #pragma unroll
                for (int hs = 0; hs < 2; ++hs) {
                    float s = hs ? s2.y : s2.x;
                    int kk = 2*i + hs;
                    bool sel = (s >= thr);
                    float w = sel ? __expf(s - m) : 0.f;
                    sw += w;
                    if (__any(sel)) {
                        const float4* vv = (const float4*)(vbW + kk*36);
                        #pragma unroll
                        for (int r = 0; r < 8; ++r) {
                            float4 vvv = vv[r];
                            acc[4*r]   = fmaf(w, vvv.x, acc[4*r]);
                            acc[4*r+1] = fmaf(w, vvv.y, acc[4*r+1]);
                            acc[4*r+2] = fmaf(w, vvv.z, acc[4*r+2]);
                            acc[4*r+3] = fmaf(w, vvv.w, acc[4*r+3]);
                        }
                    }
                }
            }
            if (c + 1 < 32) {
                convwrite_k(k0, k1);
                float* wp = vbW + skey*36 + sgrp*8;
                *(float4*)wp = v0; *(float4*)(wp + 4) = v1;
            }
        }
    }

    // publish acc partials into own arena (kbuf/sc/vb dead)
    #pragma unroll
    for (int d = 0; d < 32; ++d) aw[d*64 + lane] = acc[d];
    swl[wv*64 + lane] = sw;
    __syncthreads();

    float swsum = swl[lane] + swl[64+lane] + swl[128+lane] + swl[192+lane];
    float inv = 1.0f / swsum;
    float* orow = o + ((size_t)(b*NN + tile*64 + lane))*DD + head*DHH;
    #pragma unroll
    for (int dd = 0; dd < 8; ++dd) {
        int d = 8*wv + dd;
        float sv = arena[0][d*64+lane] + arena[1][d*64+lane]
                 + arena[2][d*64+lane] + arena[3][d*64+lane];
        orow[d] = sv * inv;
    }
}

// ---------------- K4: out_pre = lowrank(lowrank(o)) ----------------
__global__ __launch_bounds__(64) void k_out_proj(
    const float* __restrict__ o,
    const float* __restrict__ Uo,  const float* __restrict__ Vo,  const float* __restrict__ bo,
    const float* __restrict__ Uop, const float* __restrict__ Vop, const float* __restrict__ bop,
    float* __restrict__ outp)
{
    const int row = blockIdx.x, lane = threadIdx.x;
    __shared__ float buf[DD];
    __shared__ float ts[RR];
    const float* orow = o + (size_t)row * DD;
    { float4 t4 = ((const float4*)orow)[lane];
      buf[lane*4]=t4.x; buf[lane*4+1]=t4.y; buf[lane*4+2]=t4.z; buf[lane*4+3]=t4.w; }
    __syncthreads();
    float t = 0.f;
    for (int d = 0; d < DD; ++d) t = fmaf(buf[d], Uo[d*RR + lane], t);
    ts[lane] = t;
    __syncthreads();
    float a[4];
    #pragma unroll
    for (int j = 0; j < 4; ++j) a[j] = bo[lane + 64*j];
    for (int r = 0; r < RR; ++r) {
        float tv = ts[r];
        #pragma unroll
        for (int j = 0; j < 4; ++j) a[j] = fmaf(tv, Vo[r*DD + lane + 64*j], a[j]);
    }
    __syncthreads();
    #pragma unroll
    for (int j = 0; j < 4; ++j) buf[lane + 64*j] = a[j];
    __syncthreads();
    float t2 = 0.f;
    for (int d = 0; d < DD; ++d) t2 = fmaf(buf[d], Uop[d*RR + lane], t2);
    __syncthreads();
    ts[lane] = t2;
    __syncthreads();
    float c[4];
    #pragma unroll
    for (int j = 0; j < 4; ++j) c[j] = bop[lane + 64*j];
    for (int r = 0; r < RR; ++r) {
        float tv = ts[r];
        #pragma unroll
        for (int j = 0; j < 4; ++j) c[j] = fmaf(tv, Vop[r*DD + lane + 64*j], c[j]);
    }
    float* orow_out = outp + (size_t)row * DD;
    #pragma unroll
    for (int j = 0; j < 4; ++j) orow_out[lane + 64*j] = c[j];
}

// ---------------- K5a: BN partial sums (coalesced; thread = channel) ----------------
__global__ __launch_bounds__(256) void k_bnpart(
    const float* __restrict__ outp, float* __restrict__ part)
{
    const int blk = blockIdx.x, t = threadIdx.x;   // 128 blocks x 64 rows
    const float* p = outp + (size_t)blk*64*DD + t;
    float s = 0.f, s2 = 0.f;
    #pragma unroll 4
    for (int r = 0; r < 64; ++r) {
        float v = p[(size_t)r*DD];
        s += v; s2 += v*v;
    }
    part[blk*512 + t]       = s;
    part[blk*512 + 256 + t] = s2;
}

// ---------------- K5b: finalize stats ----------------
__global__ __launch_bounds__(256) void k_bnfin(
    const float* __restrict__ part, float* __restrict__ stats,
    const float* __restrict__ gamma, const float* __restrict__ beta)
{
    const int c = threadIdx.x;
    float s = 0.f, s2 = 0.f;
    for (int j = 0; j < 128; ++j) {
        s  += part[j*512 + c];
        s2 += part[j*512 + 256 + c];
    }
    float mean = s * (1.0f/ROWS);
    float var  = s2 * (1.0f/ROWS) - mean*mean;
    float inv  = rsqrtf(var + 1e-5f);
    float g = gamma[c], be = beta[c];
    stats[c]      = g * inv;
    stats[DD + c] = be - mean * g * inv;
}

// ---------------- K6: apply BN (fp32 out) ----------------
__global__ __launch_bounds__(256) void k_bnapply(
    const float* __restrict__ outp, const float* __restrict__ stats,
    float* __restrict__ out)
{
    const size_t idx = (size_t)blockIdx.x * 256 + threadIdx.x;
    const int c = (int)(idx & (DD-1));
    out[idx] = outp[idx] * stats[c] + stats[DD + c];
}

extern "C" void kernel_launch(void* const* d_in, const int* in_sizes, int n_in,
                              void* d_out, int out_size, void* d_ws, size_t ws_size,
                              hipStream_t stream)
{
    (void)in_sizes; (void)n_in; (void)out_size; (void)ws_size;
    const float* x    = (const float*)d_in[0];
    const float* U_np = (const float*)d_in[1];
    const float* V_np = (const float*)d_in[2];
    const float* b_np = (const float*)d_in[3];
    const float* U_q  = (const float*)d_in[4];
    const float* V_q  = (const float*)d_in[5];
    const float* U_k  = (const float*)d_in[6];
    const float* V_k  = (const float*)d_in[7];
    const float* U_v  = (const float*)d_in[8];
    const float* V_v  = (const float*)d_in[9];
    const float* U_o  = (const float*)d_in[10];
    const float* V_o  = (const float*)d_in[11];
    const float* b_o  = (const float*)d_in[12];
    const float* U_op = (const float*)d_in[13];
    const float* V_op = (const float*)d_in[14];
    const float* b_op = (const float*)d_in[15];
    const float* gamma= (const float*)d_in[16];
    const float* beta = (const float*)d_in[17];

    float* ws  = (float*)d_ws;
    float* out = (float*)d_out;
    const size_t BUF = (size_t)ROWS * DD;     // 2,097,152 floats = 8 MB

    float* h    = out;        // K1 writes, K2 reads, dead after
    float* q    = ws;
    float* k    = ws + BUF;
    float* v    = ws + 2*BUF;
    float* o    = out;        // K3 writes (h dead), K4 reads
    float* outp = q;          // K4 writes (q dead), K5/K6 read
    float* stats= k;          // 512 floats (k dead after attn)
    float* part = v;          // 128*512 floats (v dead after attn)

    k_node_proj<<<ROWS, 64, 0, stream>>>(x, U_np, V_np, b_np, h);
    k_qkv<<<ROWS, 64, 0, stream>>>(h, U_q, V_q, U_k, V_k, U_v, V_v, q, k, v);
    k_attn<<<BB*HH*32, 256, 0, stream>>>(q, k, v, o);
    k_out_proj<<<ROWS, 64, 0, stream>>>(o, U_o, V_o, b_o, U_op, V_op, b_op, outp);
    k_bnpart<<<128, 256, 0, stream>>>(outp, part);
    k_bnfin<<<1, 256, 0, stream>>>(part, stats, gamma, beta);
    k_bnapply<<<ROWS, 256, 0, stream>>>(outp, stats, out);
}

// Round 14
// 470.624 us; speedup vs baseline: 8.2835x; 1.0880x over previous
//
#include <hip/hip_runtime.h>
#include <hip/hip_bf16.h>

#define BB 4
#define NN 2048
#define DD 256
#define HH 8
#define RR 64
#define DHH 32
#define KSP 32
#define ROWS (BB*NN)   // 8192
#define NEG_INF (-3.0e38f)

typedef __attribute__((ext_vector_type(8))) short bf16x8;
typedef __attribute__((ext_vector_type(4))) float f32x4;
#define MFMA16(A,B,C) __builtin_amdgcn_mfma_f32_16x16x32_bf16((A),(B),(C),0,0,0)

// ---------------- K1: h = (x @ U_np) @ V_np + b_np ----------------
__global__ __launch_bounds__(64) void k_node_proj(
    const float* __restrict__ x, const float* __restrict__ U,
    const float* __restrict__ V, const float* __restrict__ bias,
    float* __restrict__ h)
{
    const int row = blockIdx.x, lane = threadIdx.x;
    __shared__ float xs[DD];
    __shared__ float ts[RR];
    const float* xr = x + (size_t)row * DD;
    { float4 t4 = ((const float4*)xr)[lane];
      xs[lane*4]=t4.x; xs[lane*4+1]=t4.y; xs[lane*4+2]=t4.z; xs[lane*4+3]=t4.w; }
    __syncthreads();
    float t = 0.f;
    for (int d = 0; d < DD; ++d) t = fmaf(xs[d], U[d*RR + lane], t);
    ts[lane] = t;
    __syncthreads();
    float a[4];
    #pragma unroll
    for (int j = 0; j < 4; ++j) a[j] = bias[lane + 64*j];
    for (int r = 0; r < RR; ++r) {
        float tv = ts[r];
        const float* Vr = V + r*DD + lane;
        #pragma unroll
        for (int j = 0; j < 4; ++j) a[j] = fmaf(tv, Vr[64*j], a[j]);
    }
    float* hr = h + (size_t)row * DD;
    #pragma unroll
    for (int j = 0; j < 4; ++j) hr[lane + 64*j] = a[j];
}

// ---------------- K2: q,k,v = lowrank(h), kept in [B,N,D] layout ----------------
__global__ __launch_bounds__(64) void k_qkv(
    const float* __restrict__ h,
    const float* __restrict__ Uq, const float* __restrict__ Vq,
    const float* __restrict__ Uk, const float* __restrict__ Vk,
    const float* __restrict__ Uv, const float* __restrict__ Vv,
    float* __restrict__ q, float* __restrict__ k, float* __restrict__ v)
{
    const int row = blockIdx.x, lane = threadIdx.x;
    __shared__ float hs[DD];
    __shared__ float tq[RR], tk[RR], tvv[RR];
    const float* hr = h + (size_t)row * DD;
    { float4 t4 = ((const float4*)hr)[lane];
      hs[lane*4]=t4.x; hs[lane*4+1]=t4.y; hs[lane*4+2]=t4.z; hs[lane*4+3]=t4.w; }
    __syncthreads();
    float aq=0.f, ak=0.f, av=0.f;
    for (int d = 0; d < DD; ++d) {
        float hv = hs[d];
        aq = fmaf(hv, Uq[d*RR + lane], aq);
        ak = fmaf(hv, Uk[d*RR + lane], ak);
        av = fmaf(hv, Uv[d*RR + lane], av);
    }
    tq[lane]=aq; tk[lane]=ak; tvv[lane]=av;
    __syncthreads();
    float oq[4], ok[4], ov[4];
    #pragma unroll
    for (int j = 0; j < 4; ++j) { oq[j]=0.f; ok[j]=0.f; ov[j]=0.f; }
    for (int r = 0; r < RR; ++r) {
        float sq=tq[r], sk=tk[r], sv=tvv[r];
        const int base = r*DD + lane;
        #pragma unroll
        for (int j = 0; j < 4; ++j) {
            oq[j] = fmaf(sq, Vq[base + 64*j], oq[j]);
            ok[j] = fmaf(sk, Vk[base + 64*j], ok[j]);
            ov[j] = fmaf(sv, Vv[base + 64*j], ov[j]);
        }
    }
    float* qr = q + (size_t)row * DD;
    float* kr = k + (size_t)row * DD;
    float* vr = v + (size_t)row * DD;
    #pragma unroll
    for (int j = 0; j < 4; ++j) {
        qr[lane + 64*j] = oq[j];
        kr[lane + 64*j] = ok[j];
        vr[lane + 64*j] = ov[j];
    }
}

__device__ __forceinline__ unsigned short f2bf(float x) {
    __hip_bfloat16 h = __float2bfloat16(x);
    return *reinterpret_cast<unsigned short*>(&h);
}
__device__ __forceinline__ float bf2f(unsigned short u) {
    __hip_bfloat16 h; *reinterpret_cast<unsigned short*>(&h) = u;
    return __bfloat162float(h);
}
// 3-way bf16 split: x = b1 + b2 + b3 + O(2^-27 x)
__device__ __forceinline__ void split3(float x, unsigned short& b1,
                                       unsigned short& b2, unsigned short& b3) {
    b1 = f2bf(x);        float f1 = bf2f(b1);
    float r = x - f1;    b2 = f2bf(r);
    float f2 = bf2f(b2); float r2 = r - f2;
    b3 = f2bf(r2);
}

// compare-exchange (ascending)
#define CEX(a_, b_) { float _l = fminf(a_, b_); (b_) = fmaxf(a_, b_); (a_) = _l; }

// ---------------- K3: sparse top-32 attention, MFMA bf16x3 scores ----------------
// Round-13 structure with the spill fixed: plane-3 Q fragments live in block-
// shared LDS (identical across the 4 waves; written once by wave 0), freeing
// 16 VGPRs -> pass-1 live set ~111 regs. waves_per_eu(3,4): min budget 170
// (never forces spill), max 4 (allows 4 waves/EU when alloc <=128).
// LDS 37 KB -> 4 blocks/CU. All arithmetic bit-identical to round 13.
__global__ __launch_bounds__(256)
__attribute__((amdgpu_waves_per_eu(3, 4)))
void k_attn(
    const float* __restrict__ qx, const float* __restrict__ kx,
    const float* __restrict__ vx, float* __restrict__ o)
{
    __shared__ float arena[4][2048];   // per-wave: kbuf(960)&scW(1152) aliased @0; vbW @1152; publish 2048
    __shared__ float swl[256];
    __shared__ uint4 q3buf[256];       // 4 KB: plane-3 A-fragments [tile][lane], block-shared
    const int tid  = threadIdx.x;
    const int lane = tid & 63;
    const int wv   = tid >> 6;
    const int blk  = blockIdx.x;
    const int tile = blk & 31;
    const int head = (blk >> 5) & 7;
    const int b    = blk >> 8;
    const float scale = 0.17677669529663687f;  // 1/sqrt(32)

    float* aw  = arena[wv];
    unsigned int* kbu = (unsigned int*)aw;   // [3][16][20] uints (bf16 pairs) — aliased with scW
    float* scW = aw;                         // [64][18] scores — SAME region (in-order DS)
    float* vbW = aw + 1152;                  // [16][36] V chunk

    const float* Kb = kx + (size_t)b*NN*DD + head*DHH;
    const float* Vb = vx + (size_t)b*NN*DD + head*DHH;
    const int j0 = wv*512;

    // ---- A fragments: Q tiles (scaled), 3-way bf16 split ----
    // planes 1,2 in registers; plane 3 to block LDS (identical across waves)
    bf16x8 aq[4][2];
    {
        const int qr = lane & 15, ko = (lane >> 4) * 8;
        const float* qbase = qx + ((size_t)(b*NN + tile*64))*DD + head*DHH + ko;
        #pragma unroll
        for (int t = 0; t < 4; ++t) {
            const float* qp = qbase + (size_t)(t*16 + qr)*DD;
            float4 x0 = ((const float4*)qp)[0];
            float4 x1 = ((const float4*)qp)[1];
            float xv[8] = {x0.x,x0.y,x0.z,x0.w,x1.x,x1.y,x1.z,x1.w};
            unsigned int w3[4];
            #pragma unroll
            for (int i = 0; i < 4; ++i) {
                unsigned short a1,a2,a3, b1,b2,b3;
                split3(xv[2*i]*scale,   a1, a2, a3);
                split3(xv[2*i+1]*scale, b1, b2, b3);
                aq[t][0][2*i]   = (short)a1;  aq[t][0][2*i+1] = (short)b1;
                aq[t][1][2*i]   = (short)a2;  aq[t][1][2*i+1] = (short)b2;
                w3[i] = (unsigned int)a3 | ((unsigned int)b3 << 16);
            }
            if (wv == 0) q3buf[t*64 + lane] = make_uint4(w3[0],w3[1],w3[2],w3[3]);
        }
    }
    __syncthreads();   // q3buf visible to all waves

    // staging role: lane -> (key = lane>>2, grp = lane&3 covering 8 dims)
    const int skey = lane >> 2, sgrp = lane & 3;
    const float* kSrc = Kb + (size_t)skey*DD + sgrp*8;
    const float* vSrc = Vb + (size_t)skey*DD + sgrp*8;

    auto convwrite_k = [&](float4 f0, float4 f1) {
        float xv[8] = {f0.x,f0.y,f0.z,f0.w,f1.x,f1.y,f1.z,f1.w};
        unsigned int w1[4], w2[4], w3[4];
        #pragma unroll
        for (int i = 0; i < 4; ++i) {
            unsigned short a0,b0,c0,a1,b1,c1;
            split3(xv[2*i],   a0, b0, c0);
            split3(xv[2*i+1], a1, b1, c1);
            w1[i] = (unsigned int)a0 | ((unsigned int)a1 << 16);
            w2[i] = (unsigned int)b0 | ((unsigned int)b1 << 16);
            w3[i] = (unsigned int)c0 | ((unsigned int)c1 << 16);
        }
        *(uint4*)(kbu + ( 0 + skey)*20 + sgrp*4) = make_uint4(w1[0],w1[1],w1[2],w1[3]);
        *(uint4*)(kbu + (16 + skey)*20 + sgrp*4) = make_uint4(w2[0],w2[1],w2[2],w2[3]);
        *(uint4*)(kbu + (32 + skey)*20 + sgrp*4) = make_uint4(w3[0],w3[1],w3[2],w3[3]);
    };

    // scores for chunk in kbuf -> scW[64][18]; IDENTICAL both passes.
    // Summation order matches round 13 exactly (q3k1 term now sourced from LDS).
    auto scores_chunk = [&]() {
        const unsigned short* kb16 = (const unsigned short*)kbu;
        const int key = lane & 15, ko = (lane >> 4) * 8;
        bf16x8 bk0 = *(const bf16x8*)(kb16 + ( 0 + key)*40 + ko);
        bf16x8 bk1 = *(const bf16x8*)(kb16 + (16 + key)*40 + ko);
        bf16x8 bk2 = *(const bf16x8*)(kb16 + (32 + key)*40 + ko);
        const int qr0 = (lane >> 4) * 4;
        #pragma unroll
        for (int t = 0; t < 4; ++t) {
            uint4 qw = q3buf[t*64 + lane];
            bf16x8 q3 = *reinterpret_cast<const bf16x8*>(&qw);
            f32x4 c4 = {0.f, 0.f, 0.f, 0.f};
            c4 = MFMA16(aq[t][0], bk0, c4);   // q1k1
            c4 = MFMA16(aq[t][0], bk1, c4);   // q1k2
            c4 = MFMA16(aq[t][1], bk0, c4);   // q2k1
            c4 = MFMA16(aq[t][0], bk2, c4);   // q1k3
            c4 = MFMA16(q3,       bk0, c4);   // q3k1
            c4 = MFMA16(aq[t][1], bk1, c4);   // q2k2
            #pragma unroll
            for (int r = 0; r < 4; ++r)
                scW[(t*16 + qr0 + r)*18 + key] = c4[r];
        }
    };

    // ---- exact batch merge of 16 new scores into sorted-asc t32[32] ----
    auto merge_batch = [&](float* t, float* sb) {
        #pragma unroll
        for (int i = 0; i < 8; ++i) CEX(sb[2*i], sb[2*i+1]);
        #pragma unroll
        for (int g = 0; g < 4; ++g) { CEX(sb[4*g], sb[4*g+2]); CEX(sb[4*g+1], sb[4*g+3]); }
        #pragma unroll
        for (int g = 0; g < 4; ++g) CEX(sb[4*g+1], sb[4*g+2]);
        #pragma unroll
        for (int g = 0; g < 2; ++g) {
            CEX(sb[8*g],   sb[8*g+4]); CEX(sb[8*g+1], sb[8*g+5]);
            CEX(sb[8*g+2], sb[8*g+6]); CEX(sb[8*g+3], sb[8*g+7]);
        }
        #pragma unroll
        for (int g = 0; g < 2; ++g) { CEX(sb[8*g+2], sb[8*g+4]); CEX(sb[8*g+3], sb[8*g+5]); }
        #pragma unroll
        for (int g = 0; g < 2; ++g) {
            CEX(sb[8*g+1], sb[8*g+2]); CEX(sb[8*g+3], sb[8*g+4]); CEX(sb[8*g+5], sb[8*g+6]);
        }
        #pragma unroll
        for (int i = 0; i < 8; ++i) CEX(sb[i], sb[i+8]);
        #pragma unroll
        for (int i = 0; i < 4; ++i) CEX(sb[i+4], sb[i+8]);
        #pragma unroll
        for (int g = 0; g < 3; ++g) { CEX(sb[4*g+2], sb[4*g+4]); CEX(sb[4*g+3], sb[4*g+5]); }
        #pragma unroll
        for (int i = 0; i < 7; ++i) CEX(sb[2*i+1], sb[2*i+2]);
        // pairing (drop the 16 provably-out elements)
        float u[16];
        #pragma unroll
        for (int i = 0; i < 16; ++i) u[i] = fmaxf(t[i], sb[15-i]);
        // u is bitonic -> ascending
        #pragma unroll
        for (int st = 8; st >= 1; st >>= 1)
            #pragma unroll
            for (int i = 0; i < 16; ++i)
                if ((i & st) == 0) CEX(u[i], u[i+st]);
        // half-cleaner of [u asc | t_hi desc]
        #pragma unroll
        for (int i = 0; i < 8; ++i) {
            float hi1 = t[31-i], hi2 = t[16+i];
            float u1 = u[i],     u2 = u[15-i];
            t[i]    = fminf(u1, hi1);
            t[31-i] = fmaxf(u1, hi1);
            t[15-i] = fminf(u2, hi2);
            t[16+i] = fmaxf(u2, hi2);
        }
        #pragma unroll
        for (int st = 8; st >= 1; st >>= 1)
            #pragma unroll
            for (int i = 0; i < 32; ++i)
                if ((i & st) == 0) CEX(t[i], t[i+st]);
    };

    // ---------------- pass 1: exact per-query top-32 ----------------
    float t32[32];
    #pragma unroll
    for (int i = 0; i < 32; ++i) t32[i] = NEG_INF;

    {
        float4 k0, k1;
        { const float* p = kSrc + (size_t)j0*DD;
          k0 = ((const float4*)p)[0]; k1 = ((const float4*)p)[1]; }
        convwrite_k(k0, k1);
        for (int c = 0; c < 32; ++c) {
            if (c + 1 < 32) {
                const float* p = kSrc + (size_t)(j0 + (c+1)*16)*DD;
                k0 = ((const float4*)p)[0]; k1 = ((const float4*)p)[1];
            }
            scores_chunk();
            {
                const float2* sp = (const float2*)(scW + lane*18);
                float sb[16];
                #pragma unroll
                for (int i = 0; i < 8; ++i) { float2 v2 = sp[i]; sb[2*i] = v2.x; sb[2*i+1] = v2.y; }
                merge_batch(t32, sb);
            }
            if (c + 1 < 32) convwrite_k(k0, k1);
        }
    }
    #pragma unroll
    for (int i = 0; i < 32; ++i) aw[i*64 + lane] = t32[i];
    __syncthreads();

    // ---- merge 4 sorted lists: exact m (pick 0) and thr (pick 31) ----
    int i0=31, i1=31, i2=31, i3=31;
    float m = NEG_INF, thr = NEG_INF;
    for (int p = 0; p < 32; ++p) {
        float v0 = arena[0][i0*64 + lane];
        float v1 = arena[1][i1*64 + lane];
        float v2 = arena[2][i2*64 + lane];
        float v3 = arena[3][i3*64 + lane];
        float vm = fmaxf(fmaxf(v0,v1), fmaxf(v2,v3));
        if (p == 0) m = vm;
        thr = vm;
        if      (vm == v0) --i0;
        else if (vm == v1) --i1;
        else if (vm == v2) --i2;
        else               --i3;
    }
    __syncthreads();   // all waves done reading lists before arena reuse

    // ---------------- pass 2: recompute (identical), select s>=thr, PV ------
    float acc[32];
    #pragma unroll
    for (int d = 0; d < 32; ++d) acc[d] = 0.f;
    float sw = 0.f;

    {
        float4 k0, k1, v0, v1;
        { const float* p = kSrc + (size_t)j0*DD;
          k0 = ((const float4*)p)[0]; k1 = ((const float4*)p)[1]; }
        { const float* p = vSrc + (size_t)j0*DD;
          v0 = ((const float4*)p)[0]; v1 = ((const float4*)p)[1]; }
        convwrite_k(k0, k1);
        { float* wp = vbW + skey*36 + sgrp*8;
          *(float4*)wp = v0; *(float4*)(wp + 4) = v1; }
        for (int c = 0; c < 32; ++c) {
            if (c + 1 < 32) {
                const float* p = kSrc + (size_t)(j0 + (c+1)*16)*DD;
                k0 = ((const float4*)p)[0]; k1 = ((const float4*)p)[1];
                const float* pv = vSrc + (size_t)(j0 + (c+1)*16)*DD;
                v0 = ((const float4*)pv)[0]; v1 = ((const float4*)pv)[1];
            }
            scores_chunk();
            const float2* sp = (const float2*)(scW + lane*18);
            #pragma unroll
            for (int i = 0; i < 8; ++i) {
                float2 s2 = sp[i];
                #pragma unroll
                for (int hs = 0; hs < 2; ++hs) {
                    float s = hs ? s2.y : s2.x;
                    int kk = 2*i + hs;
                    bool sel = (s >= thr);
                    float w = sel ? __expf(s - m) : 0.f;
                    sw += w;
                    if (__any(sel)) {
                        const float4* vv = (const float4*)(vbW + kk*36);
                        #pragma unroll
                        for (int r = 0; r < 8; ++r) {
                            float4 vvv = vv[r];
                            acc[4*r]   = fmaf(w, vvv.x, acc[4*r]);
                            acc[4*r+1] = fmaf(w, vvv.y, acc[4*r+1]);
                            acc[4*r+2] = fmaf(w, vvv.z, acc[4*r+2]);
                            acc[4*r+3] = fmaf(w, vvv.w, acc[4*r+3]);
                        }
                    }
                }
            }
            if (c + 1 < 32) {
                convwrite_k(k0, k1);
                float* wp = vbW + skey*36 + sgrp*8;
                *(float4*)wp = v0; *(float4*)(wp + 4) = v1;
            }
        }
    }

    // publish acc partials into own arena (kbuf/sc/vb dead)
    #pragma unroll
    for (int d = 0; d < 32; ++d) aw[d*64 + lane] = acc[d];
    swl[wv*64 + lane] = sw;
    __syncthreads();

    float swsum = swl[lane] + swl[64+lane] + swl[128+lane] + swl[192+lane];
    float inv = 1.0f / swsum;
    float* orow = o + ((size_t)(b*NN + tile*64 + lane))*DD + head*DHH;
    #pragma unroll
    for (int dd = 0; dd < 8; ++dd) {
        int d = 8*wv + dd;
        float sv = arena[0][d*64+lane] + arena[1][d*64+lane]
                 + arena[2][d*64+lane] + arena[3][d*64+lane];
        orow[d] = sv * inv;
    }
}

// ---------------- K4: out_pre = lowrank(lowrank(o)) ----------------
__global__ __launch_bounds__(64) void k_out_proj(
    const float* __restrict__ o,
    const float* __restrict__ Uo,  const float* __restrict__ Vo,  const float* __restrict__ bo,
    const float* __restrict__ Uop, const float* __restrict__ Vop, const float* __restrict__ bop,
    float* __restrict__ outp)
{
    const int row = blockIdx.x, lane = threadIdx.x;
    __shared__ float buf[DD];
    __shared__ float ts[RR];
    const float* orow = o + (size_t)row * DD;
    { float4 t4 = ((const float4*)orow)[lane];
      buf[lane*4]=t4.x; buf[lane*4+1]=t4.y; buf[lane*4+2]=t4.z; buf[lane*4+3]=t4.w; }
    __syncthreads();
    float t = 0.f;
    for (int d = 0; d < DD; ++d) t = fmaf(buf[d], Uo[d*RR + lane], t);
    ts[lane] = t;
    __syncthreads();
    float a[4];
    #pragma unroll
    for (int j = 0; j < 4; ++j) a[j] = bo[lane + 64*j];
    for (int r = 0; r < RR; ++r) {
        float tv = ts[r];
        #pragma unroll
        for (int j = 0; j < 4; ++j) a[j] = fmaf(tv, Vo[r*DD + lane + 64*j], a[j]);
    }
    __syncthreads();
    #pragma unroll
    for (int j = 0; j < 4; ++j) buf[lane + 64*j] = a[j];
    __syncthreads();
    float t2 = 0.f;
    for (int d = 0; d < DD; ++d) t2 = fmaf(buf[d], Uop[d*RR + lane], t2);
    __syncthreads();
    ts[lane] = t2;
    __syncthreads();
    float c[4];
    #pragma unroll
    for (int j = 0; j < 4; ++j) c[j] = bop[lane + 64*j];
    for (int r = 0; r < RR; ++r) {
        float tv = ts[r];
        #pragma unroll
        for (int j = 0; j < 4; ++j) c[j] = fmaf(tv, Vop[r*DD + lane + 64*j], c[j]);
    }
    float* orow_out = outp + (size_t)row * DD;
    #pragma unroll
    for (int j = 0; j < 4; ++j) orow_out[lane + 64*j] = c[j];
}

// ---------------- K5a: BN partial sums (coalesced; thread = channel) ----------------
__global__ __launch_bounds__(256) void k_bnpart(
    const float* __restrict__ outp, float* __restrict__ part)
{
    const int blk = blockIdx.x, t = threadIdx.x;   // 128 blocks x 64 rows
    const float* p = outp + (size_t)blk*64*DD + t;
    float s = 0.f, s2 = 0.f;
    #pragma unroll 4
    for (int r = 0; r < 64; ++r) {
        float v = p[(size_t)r*DD];
        s += v; s2 += v*v;
    }
    part[blk*512 + t]       = s;
    part[blk*512 + 256 + t] = s2;
}

// ---------------- K5b: finalize stats ----------------
__global__ __launch_bounds__(256) void k_bnfin(
    const float* __restrict__ part, float* __restrict__ stats,
    const float* __restrict__ gamma, const float* __restrict__ beta)
{
    const int c = threadIdx.x;
    float s = 0.f, s2 = 0.f;
    for (int j = 0; j < 128; ++j) {
        s  += part[j*512 + c];
        s2 += part[j*512 + 256 + c];
    }
    float mean = s * (1.0f/ROWS);
    float var  = s2 * (1.0f/ROWS) - mean*mean;
    float inv  = rsqrtf(var + 1e-5f);
    float g = gamma[c], be = beta[c];
    stats[c]      = g * inv;
    stats[DD + c] = be - mean * g * inv;
}

// ---------------- K6: apply BN (fp32 out) ----------------
__global__ __launch_bounds__(256) void k_bnapply(
    const float* __restrict__ outp, const float* __restrict__ stats,
    float* __restrict__ out)
{
    const size_t idx = (size_t)blockIdx.x * 256 + threadIdx.x;
    const int c = (int)(idx & (DD-1));
    out[idx] = outp[idx] * stats[c] + stats[DD + c];
}

extern "C" void kernel_launch(void* const* d_in, const int* in_sizes, int n_in,
                              void* d_out, int out_size, void* d_ws, size_t ws_size,
                              hipStream_t stream)
{
    (void)in_sizes; (void)n_in; (void)out_size; (void)ws_size;
    const float* x    = (const float*)d_in[0];
    const float* U_np = (const float*)d_in[1];
    const float* V_np = (const float*)d_in[2];
    const float* b_np = (const float*)d_in[3];
    const float* U_q  = (const float*)d_in[4];
    const float* V_q  = (const float*)d_in[5];
    const float* U_k  = (const float*)d_in[6];
    const float* V_k  = (const float*)d_in[7];
    const float* U_v  = (const float*)d_in[8];
    const float* V_v  = (const float*)d_in[9];
    const float* U_o  = (const float*)d_in[10];
    const float* V_o  = (const float*)d_in[11];
    const float* b_o  = (const float*)d_in[12];
    const float* U_op = (const float*)d_in[13];
    const float* V_op = (const float*)d_in[14];
    const float* b_op = (const float*)d_in[15];
    const float* gamma= (const float*)d_in[16];
    const float* beta = (const float*)d_in[17];

    float* ws  = (float*)d_ws;
    float* out = (float*)d_out;
    const size_t BUF = (size_t)ROWS * DD;     // 2,097,152 floats = 8 MB

    float* h    = out;        // K1 writes, K2 reads, dead after
    float* q    = ws;
    float* k    = ws + BUF;
    float* v    = ws + 2*BUF;
    float* o    = out;        // K3 writes (h dead), K4 reads
    float* outp = q;          // K4 writes (q dead), K5/K6 read
    float* stats= k;          // 512 floats (k dead after attn)
    float* part = v;          // 128*512 floats (v dead after attn)

    k_node_proj<<<ROWS, 64, 0, stream>>>(x, U_np, V_np, b_np, h);
    k_qkv<<<ROWS, 64, 0, stream>>>(h, U_q, V_q, U_k, V_k, U_v, V_v, q, k, v);
    k_attn<<<BB*HH*32, 256, 0, stream>>>(q, k, v, o);
    k_out_proj<<<ROWS, 64, 0, stream>>>(o, U_o, V_o, b_o, U_op, V_op, b_op, outp);
    k_bnpart<<<128, 256, 0, stream>>>(outp, part);
    k_bnfin<<<1, 256, 0, stream>>>(part, stats, gamma, beta);
    k_bnapply<<<ROWS, 256, 0, stream>>>(outp, stats, out);
}

// Round 15
// 434.922 us; speedup vs baseline: 8.9635x; 1.0821x over previous
//
#include <hip/hip_runtime.h>
#include <hip/hip_bf16.h>

#define BB 4
#define NN 2048
#define DD 256
#define HH 8
#define RR 64
#define DHH 32
#define KSP 32
#define ROWS (BB*NN)   // 8192
#define NEG_INF (-3.0e38f)
#define SSTR 19        // score row stride: odd -> b32 reads 2-way (free)

typedef __attribute__((ext_vector_type(8))) short bf16x8;
typedef __attribute__((ext_vector_type(4))) float f32x4;
#define MFMA16(A,B,C) __builtin_amdgcn_mfma_f32_16x16x32_bf16((A),(B),(C),0,0,0)

// ---------------- K1: h = (x @ U_np) @ V_np + b_np  (8 rows/block) ----------------
__global__ __launch_bounds__(64) void k_node_proj(
    const float* __restrict__ x, const float* __restrict__ U,
    const float* __restrict__ V, const float* __restrict__ bias,
    float* __restrict__ h)
{
    const int blk = blockIdx.x, lane = threadIdx.x;
    const int row0 = blk * 8;
    __shared__ float xs[8][DD];
    __shared__ float ts[8][RR];
    #pragma unroll
    for (int r = 0; r < 8; ++r) {
        float4 t4 = ((const float4*)(x + (size_t)(row0 + r)*DD))[lane];
        *(float4*)&xs[r][lane*4] = t4;
    }
    __syncthreads();
    float t[8];
    #pragma unroll
    for (int r = 0; r < 8; ++r) t[r] = 0.f;
    for (int d = 0; d < DD; ++d) {
        float u = U[d*RR + lane];
        #pragma unroll
        for (int r = 0; r < 8; ++r) t[r] = fmaf(xs[r][d], u, t[r]);
    }
    #pragma unroll
    for (int r = 0; r < 8; ++r) ts[r][lane] = t[r];
    __syncthreads();
    float a[8][4];
    #pragma unroll
    for (int r = 0; r < 8; ++r)
        #pragma unroll
        for (int j = 0; j < 4; ++j) a[r][j] = bias[lane + 64*j];
    for (int rr = 0; rr < RR; ++rr) {
        float tv[8];
        #pragma unroll
        for (int r = 0; r < 8; ++r) tv[r] = ts[r][rr];
        const float* Vr = V + rr*DD + lane;
        #pragma unroll
        for (int j = 0; j < 4; ++j) {
            float vv = Vr[64*j];
            #pragma unroll
            for (int r = 0; r < 8; ++r) a[r][j] = fmaf(tv[r], vv, a[r][j]);
        }
    }
    #pragma unroll
    for (int r = 0; r < 8; ++r) {
        float* hr = h + (size_t)(row0 + r)*DD;
        #pragma unroll
        for (int j = 0; j < 4; ++j) hr[lane + 64*j] = a[r][j];
    }
}

// ---------------- K2: q,k,v = lowrank(h)  (4 rows/block) ----------------
__global__ __launch_bounds__(64) void k_qkv(
    const float* __restrict__ h,
    const float* __restrict__ Uq, const float* __restrict__ Vq,
    const float* __restrict__ Uk, const float* __restrict__ Vk,
    const float* __restrict__ Uv, const float* __restrict__ Vv,
    float* __restrict__ q, float* __restrict__ k, float* __restrict__ v)
{
    const int blk = blockIdx.x, lane = threadIdx.x;
    const int row0 = blk * 4;
    __shared__ float hs[4][DD];
    __shared__ float tq[4][RR], tk[4][RR], tvv[4][RR];
    #pragma unroll
    for (int r = 0; r < 4; ++r) {
        float4 t4 = ((const float4*)(h + (size_t)(row0 + r)*DD))[lane];
        *(float4*)&hs[r][lane*4] = t4;
    }
    __syncthreads();
    float aq[4], ak[4], av[4];
    #pragma unroll
    for (int r = 0; r < 4; ++r) { aq[r]=0.f; ak[r]=0.f; av[r]=0.f; }
    for (int d = 0; d < DD; ++d) {
        float uq = Uq[d*RR + lane];
        float uk = Uk[d*RR + lane];
        float uv = Uv[d*RR + lane];
        #pragma unroll
        for (int r = 0; r < 4; ++r) {
            float hv = hs[r][d];
            aq[r] = fmaf(hv, uq, aq[r]);
            ak[r] = fmaf(hv, uk, ak[r]);
            av[r] = fmaf(hv, uv, av[r]);
        }
    }
    #pragma unroll
    for (int r = 0; r < 4; ++r) { tq[r][lane]=aq[r]; tk[r][lane]=ak[r]; tvv[r][lane]=av[r]; }
    __syncthreads();
    float oq[4][4], ok[4][4], ov[4][4];
    #pragma unroll
    for (int r = 0; r < 4; ++r)
        #pragma unroll
        for (int j = 0; j < 4; ++j) { oq[r][j]=0.f; ok[r][j]=0.f; ov[r][j]=0.f; }
    for (int rr = 0; rr < RR; ++rr) {
        float sq[4], sk[4], sv[4];
        #pragma unroll
        for (int r = 0; r < 4; ++r) { sq[r]=tq[r][rr]; sk[r]=tk[r][rr]; sv[r]=tvv[r][rr]; }
        const int base = rr*DD + lane;
        #pragma unroll
        for (int j = 0; j < 4; ++j) {
            float wq = Vq[base + 64*j];
            float wk = Vk[base + 64*j];
            float wv = Vv[base + 64*j];
            #pragma unroll
            for (int r = 0; r < 4; ++r) {
                oq[r][j] = fmaf(sq[r], wq, oq[r][j]);
                ok[r][j] = fmaf(sk[r], wk, ok[r][j]);
                ov[r][j] = fmaf(sv[r], wv, ov[r][j]);
            }
        }
    }
    #pragma unroll
    for (int r = 0; r < 4; ++r) {
        float* qr = q + (size_t)(row0 + r)*DD;
        float* kr = k + (size_t)(row0 + r)*DD;
        float* vr = v + (size_t)(row0 + r)*DD;
        #pragma unroll
        for (int j = 0; j < 4; ++j) {
            qr[lane + 64*j] = oq[r][j];
            kr[lane + 64*j] = ok[r][j];
            vr[lane + 64*j] = ov[r][j];
        }
    }
}

__device__ __forceinline__ unsigned short f2bf(float x) {
    __hip_bfloat16 h = __float2bfloat16(x);
    return *reinterpret_cast<unsigned short*>(&h);
}
__device__ __forceinline__ float bf2f(unsigned short u) {
    __hip_bfloat16 h; *reinterpret_cast<unsigned short*>(&h) = u;
    return __bfloat162float(h);
}
// 3-way bf16 split: x = b1 + b2 + b3 + O(2^-27 x)
__device__ __forceinline__ void split3(float x, unsigned short& b1,
                                       unsigned short& b2, unsigned short& b3) {
    b1 = f2bf(x);        float f1 = bf2f(b1);
    float r = x - f1;    b2 = f2bf(r);
    float f2 = bf2f(b2); float r2 = r - f2;
    b3 = f2bf(r2);
}

// compare-exchange (ascending)
#define CEX(a_, b_) { float _l = fminf(a_, b_); (b_) = fmaxf(a_, b_); (a_) = _l; }

// ---------------- K3: sparse top-32 attention, MFMA bf16x3 scores ----------------
// Round-14 structure; scW stride 18->19 (odd): b32 score reads become 2-way
// (free); writes worst 3-way. vbW moved to offset 1216. All math bit-identical.
__global__ __launch_bounds__(256)
__attribute__((amdgpu_waves_per_eu(3, 4)))
void k_attn(
    const float* __restrict__ qx, const float* __restrict__ kx,
    const float* __restrict__ vx, float* __restrict__ o)
{
    __shared__ float arena[4][2048];   // per-wave: kbuf(960)&scW(1216) aliased @0; vbW @1216; publish 2048
    __shared__ float swl[256];
    __shared__ uint4 q3buf[256];       // 4 KB: plane-3 A-fragments, block-shared
    const int tid  = threadIdx.x;
    const int lane = tid & 63;
    const int wv   = tid >> 6;
    const int blk  = blockIdx.x;
    const int tile = blk & 31;
    const int head = (blk >> 5) & 7;
    const int b    = blk >> 8;
    const float scale = 0.17677669529663687f;  // 1/sqrt(32)

    float* aw  = arena[wv];
    unsigned int* kbu = (unsigned int*)aw;   // [3][16][20] uints — aliased with scW
    float* scW = aw;                         // [64][SSTR] scores — SAME region (in-order DS)
    float* vbW = aw + 1216;                  // [16][36] V chunk

    const float* Kb = kx + (size_t)b*NN*DD + head*DHH;
    const float* Vb = vx + (size_t)b*NN*DD + head*DHH;
    const int j0 = wv*512;

    // ---- A fragments: planes 1,2 in regs; plane 3 in block LDS ----
    bf16x8 aq[4][2];
    {
        const int qr = lane & 15, ko = (lane >> 4) * 8;
        const float* qbase = qx + ((size_t)(b*NN + tile*64))*DD + head*DHH + ko;
        #pragma unroll
        for (int t = 0; t < 4; ++t) {
            const float* qp = qbase + (size_t)(t*16 + qr)*DD;
            float4 x0 = ((const float4*)qp)[0];
            float4 x1 = ((const float4*)qp)[1];
            float xv[8] = {x0.x,x0.y,x0.z,x0.w,x1.x,x1.y,x1.z,x1.w};
            unsigned int w3[4];
            #pragma unroll
            for (int i = 0; i < 4; ++i) {
                unsigned short a1,a2,a3, b1,b2,b3;
                split3(xv[2*i]*scale,   a1, a2, a3);
                split3(xv[2*i+1]*scale, b1, b2, b3);
                aq[t][0][2*i]   = (short)a1;  aq[t][0][2*i+1] = (short)b1;
                aq[t][1][2*i]   = (short)a2;  aq[t][1][2*i+1] = (short)b2;
                w3[i] = (unsigned int)a3 | ((unsigned int)b3 << 16);
            }
            if (wv == 0) q3buf[t*64 + lane] = make_uint4(w3[0],w3[1],w3[2],w3[3]);
        }
    }
    __syncthreads();   // q3buf visible to all waves

    const int skey = lane >> 2, sgrp = lane & 3;
    const float* kSrc = Kb + (size_t)skey*DD + sgrp*8;
    const float* vSrc = Vb + (size_t)skey*DD + sgrp*8;

    auto convwrite_k = [&](float4 f0, float4 f1) {
        float xv[8] = {f0.x,f0.y,f0.z,f0.w,f1.x,f1.y,f1.z,f1.w};
        unsigned int w1[4], w2[4], w3[4];
        #pragma unroll
        for (int i = 0; i < 4; ++i) {
            unsigned short a0,b0,c0,a1,b1,c1;
            split3(xv[2*i],   a0, b0, c0);
            split3(xv[2*i+1], a1, b1, c1);
            w1[i] = (unsigned int)a0 | ((unsigned int)a1 << 16);
            w2[i] = (unsigned int)b0 | ((unsigned int)b1 << 16);
            w3[i] = (unsigned int)c0 | ((unsigned int)c1 << 16);
        }
        *(uint4*)(kbu + ( 0 + skey)*20 + sgrp*4) = make_uint4(w1[0],w1[1],w1[2],w1[3]);
        *(uint4*)(kbu + (16 + skey)*20 + sgrp*4) = make_uint4(w2[0],w2[1],w2[2],w2[3]);
        *(uint4*)(kbu + (32 + skey)*20 + sgrp*4) = make_uint4(w3[0],w3[1],w3[2],w3[3]);
    };

    auto scores_chunk = [&]() {
        const unsigned short* kb16 = (const unsigned short*)kbu;
        const int key = lane & 15, ko = (lane >> 4) * 8;
        bf16x8 bk0 = *(const bf16x8*)(kb16 + ( 0 + key)*40 + ko);
        bf16x8 bk1 = *(const bf16x8*)(kb16 + (16 + key)*40 + ko);
        bf16x8 bk2 = *(const bf16x8*)(kb16 + (32 + key)*40 + ko);
        const int qr0 = (lane >> 4) * 4;
        #pragma unroll
        for (int t = 0; t < 4; ++t) {
            uint4 qw = q3buf[t*64 + lane];
            bf16x8 q3 = *reinterpret_cast<const bf16x8*>(&qw);
            f32x4 c4 = {0.f, 0.f, 0.f, 0.f};
            c4 = MFMA16(aq[t][0], bk0, c4);   // q1k1
            c4 = MFMA16(aq[t][0], bk1, c4);   // q1k2
            c4 = MFMA16(aq[t][1], bk0, c4);   // q2k1
            c4 = MFMA16(aq[t][0], bk2, c4);   // q1k3
            c4 = MFMA16(q3,       bk0, c4);   // q3k1
            c4 = MFMA16(aq[t][1], bk1, c4);   // q2k2
            #pragma unroll
            for (int r = 0; r < 4; ++r)
                scW[(t*16 + qr0 + r)*SSTR + key] = c4[r];
        }
    };

    // ---- exact batch merge of 16 new scores into sorted-asc t32[32] ----
    auto merge_batch = [&](float* t, float* sb) {
        #pragma unroll
        for (int i = 0; i < 8; ++i) CEX(sb[2*i], sb[2*i+1]);
        #pragma unroll
        for (int g = 0; g < 4; ++g) { CEX(sb[4*g], sb[4*g+2]); CEX(sb[4*g+1], sb[4*g+3]); }
        #pragma unroll
        for (int g = 0; g < 4; ++g) CEX(sb[4*g+1], sb[4*g+2]);
        #pragma unroll
        for (int g = 0; g < 2; ++g) {
            CEX(sb[8*g],   sb[8*g+4]); CEX(sb[8*g+1], sb[8*g+5]);
            CEX(sb[8*g+2], sb[8*g+6]); CEX(sb[8*g+3], sb[8*g+7]);
        }
        #pragma unroll
        for (int g = 0; g < 2; ++g) { CEX(sb[8*g+2], sb[8*g+4]); CEX(sb[8*g+3], sb[8*g+5]); }
        #pragma unroll
        for (int g = 0; g < 2; ++g) {
            CEX(sb[8*g+1], sb[8*g+2]); CEX(sb[8*g+3], sb[8*g+4]); CEX(sb[8*g+5], sb[8*g+6]);
        }
        #pragma unroll
        for (int i = 0; i < 8; ++i) CEX(sb[i], sb[i+8]);
        #pragma unroll
        for (int i = 0; i < 4; ++i) CEX(sb[i+4], sb[i+8]);
        #pragma unroll
        for (int g = 0; g < 3; ++g) { CEX(sb[4*g+2], sb[4*g+4]); CEX(sb[4*g+3], sb[4*g+5]); }
        #pragma unroll
        for (int i = 0; i < 7; ++i) CEX(sb[2*i+1], sb[2*i+2]);
        float u[16];
        #pragma unroll
        for (int i = 0; i < 16; ++i) u[i] = fmaxf(t[i], sb[15-i]);
        #pragma unroll
        for (int st = 8; st >= 1; st >>= 1)
            #pragma unroll
            for (int i = 0; i < 16; ++i)
                if ((i & st) == 0) CEX(u[i], u[i+st]);
        #pragma unroll
        for (int i = 0; i < 8; ++i) {
            float hi1 = t[31-i], hi2 = t[16+i];
            float u1 = u[i],     u2 = u[15-i];
            t[i]    = fminf(u1, hi1);
            t[31-i] = fmaxf(u1, hi1);
            t[15-i] = fminf(u2, hi2);
            t[16+i] = fmaxf(u2, hi2);
        }
        #pragma unroll
        for (int st = 8; st >= 1; st >>= 1)
            #pragma unroll
            for (int i = 0; i < 32; ++i)
                if ((i & st) == 0) CEX(t[i], t[i+st]);
    };

    // ---------------- pass 1: exact per-query top-32 ----------------
    float t32[32];
    #pragma unroll
    for (int i = 0; i < 32; ++i) t32[i] = NEG_INF;

    {
        float4 k0, k1;
        { const float* p = kSrc + (size_t)j0*DD;
          k0 = ((const float4*)p)[0]; k1 = ((const float4*)p)[1]; }
        convwrite_k(k0, k1);
        for (int c = 0; c < 32; ++c) {
            if (c + 1 < 32) {
                const float* p = kSrc + (size_t)(j0 + (c+1)*16)*DD;
                k0 = ((const float4*)p)[0]; k1 = ((const float4*)p)[1];
            }
            scores_chunk();
            {
                const float* sp = scW + lane*SSTR;
                float sb[16];
                #pragma unroll
                for (int i = 0; i < 16; ++i) sb[i] = sp[i];
                merge_batch(t32, sb);
            }
            if (c + 1 < 32) convwrite_k(k0, k1);
        }
    }
    #pragma unroll
    for (int i = 0; i < 32; ++i) aw[i*64 + lane] = t32[i];
    __syncthreads();

    // ---- merge 4 sorted lists: exact m (pick 0) and thr (pick 31) ----
    int i0=31, i1=31, i2=31, i3=31;
    float m = NEG_INF, thr = NEG_INF;
    for (int p = 0; p < 32; ++p) {
        float v0 = arena[0][i0*64 + lane];
        float v1 = arena[1][i1*64 + lane];
        float v2 = arena[2][i2*64 + lane];
        float v3 = arena[3][i3*64 + lane];
        float vm = fmaxf(fmaxf(v0,v1), fmaxf(v2,v3));
        if (p == 0) m = vm;
        thr = vm;
        if      (vm == v0) --i0;
        else if (vm == v1) --i1;
        else if (vm == v2) --i2;
        else               --i3;
    }
    __syncthreads();   // all waves done reading lists before arena reuse

    // ---------------- pass 2: recompute (identical), select s>=thr, PV ------
    float acc[32];
    #pragma unroll
    for (int d = 0; d < 32; ++d) acc[d] = 0.f;
    float sw = 0.f;

    {
        float4 k0, k1, v0, v1;
        { const float* p = kSrc + (size_t)j0*DD;
          k0 = ((const float4*)p)[0]; k1 = ((const float4*)p)[1]; }
        { const float* p = vSrc + (size_t)j0*DD;
          v0 = ((const float4*)p)[0]; v1 = ((const float4*)p)[1]; }
        convwrite_k(k0, k1);
        { float* wp = vbW + skey*36 + sgrp*8;
          *(float4*)wp = v0; *(float4*)(wp + 4) = v1; }
        for (int c = 0; c < 32; ++c) {
            if (c + 1 < 32) {
                const float* p = kSrc + (size_t)(j0 + (c+1)*16)*DD;
                k0 = ((const float4*)p)[0]; k1 = ((const float4*)p)[1];
                const float* pv = vSrc + (size_t)(j0 + (c+1)*16)*DD;
                v0 = ((const float4*)pv)[0]; v1 = ((const float4*)pv)[1];
            }
            scores_chunk();
            const float* sp = scW + lane*SSTR;
            #pragma unroll
            for (int kk = 0; kk < 16; ++kk) {
                float s = sp[kk];
                bool sel = (s >= thr);
                float w = sel ? __expf(s - m) : 0.f;
                sw += w;
                if (__any(sel)) {
                    const float4* vv = (const float4*)(vbW + kk*36);
                    #pragma unroll
                    for (int r = 0; r < 8; ++r) {
                        float4 vvv = vv[r];
                        acc[4*r]   = fmaf(w, vvv.x, acc[4*r]);
                        acc[4*r+1] = fmaf(w, vvv.y, acc[4*r+1]);
                        acc[4*r+2] = fmaf(w, vvv.z, acc[4*r+2]);
                        acc[4*r+3] = fmaf(w, vvv.w, acc[4*r+3]);
                    }
                }
            }
            if (c + 1 < 32) {
                convwrite_k(k0, k1);
                float* wp = vbW + skey*36 + sgrp*8;
                *(float4*)wp = v0; *(float4*)(wp + 4) = v1;
            }
        }
    }

    // publish acc partials into own arena (kbuf/sc/vb dead)
    #pragma unroll
    for (int d = 0; d < 32; ++d) aw[d*64 + lane] = acc[d];
    swl[wv*64 + lane] = sw;
    __syncthreads();

    float swsum = swl[lane] + swl[64+lane] + swl[128+lane] + swl[192+lane];
    float inv = 1.0f / swsum;
    float* orow = o + ((size_t)(b*NN + tile*64 + lane))*DD + head*DHH;
    #pragma unroll
    for (int dd = 0; dd < 8; ++dd) {
        int d = 8*wv + dd;
        float sv = arena[0][d*64+lane] + arena[1][d*64+lane]
                 + arena[2][d*64+lane] + arena[3][d*64+lane];
        orow[d] = sv * inv;
    }
}

// ---------------- K4: out_pre = lowrank(lowrank(o))  (8 rows/block) ----------------
__global__ __launch_bounds__(64) void k_out_proj(
    const float* __restrict__ o,
    const float* __restrict__ Uo,  const float* __restrict__ Vo,  const float* __restrict__ bo,
    const float* __restrict__ Uop, const float* __restrict__ Vop, const float* __restrict__ bop,
    float* __restrict__ outp)
{
    const int blk = blockIdx.x, lane = threadIdx.x;
    const int row0 = blk * 8;
    __shared__ float buf[8][DD];
    __shared__ float ts[8][RR];
    #pragma unroll
    for (int r = 0; r < 8; ++r) {
        float4 t4 = ((const float4*)(o + (size_t)(row0 + r)*DD))[lane];
        *(float4*)&buf[r][lane*4] = t4;
    }
    __syncthreads();
    // stage 1
    float t[8];
    #pragma unroll
    for (int r = 0; r < 8; ++r) t[r] = 0.f;
    for (int d = 0; d < DD; ++d) {
        float u = Uo[d*RR + lane];
        #pragma unroll
        for (int r = 0; r < 8; ++r) t[r] = fmaf(buf[r][d], u, t[r]);
    }
    #pragma unroll
    for (int r = 0; r < 8; ++r) ts[r][lane] = t[r];
    __syncthreads();
    float a[8][4];
    #pragma unroll
    for (int r = 0; r < 8; ++r)
        #pragma unroll
        for (int j = 0; j < 4; ++j) a[r][j] = bo[lane + 64*j];
    for (int rr = 0; rr < RR; ++rr) {
        float tv[8];
        #pragma unroll
        for (int r = 0; r < 8; ++r) tv[r] = ts[r][rr];
        const float* Vr = Vo + rr*DD + lane;
        #pragma unroll
        for (int j = 0; j < 4; ++j) {
            float vv = Vr[64*j];
            #pragma unroll
            for (int r = 0; r < 8; ++r) a[r][j] = fmaf(tv[r], vv, a[r][j]);
        }
    }
    __syncthreads();
    #pragma unroll
    for (int r = 0; r < 8; ++r)
        #pragma unroll
        for (int j = 0; j < 4; ++j) buf[r][lane + 64*j] = a[r][j];
    __syncthreads();
    // stage 2
    float t2[8];
    #pragma unroll
    for (int r = 0; r < 8; ++r) t2[r] = 0.f;
    for (int d = 0; d < DD; ++d) {
        float u = Uop[d*RR + lane];
        #pragma unroll
        for (int r = 0; r < 8; ++r) t2[r] = fmaf(buf[r][d], u, t2[r]);
    }
    __syncthreads();
    #pragma unroll
    for (int r = 0; r < 8; ++r) ts[r][lane] = t2[r];
    __syncthreads();
    float c2[8][4];
    #pragma unroll
    for (int r = 0; r < 8; ++r)
        #pragma unroll
        for (int j = 0; j < 4; ++j) c2[r][j] = bop[lane + 64*j];
    for (int rr = 0; rr < RR; ++rr) {
        float tv[8];
        #pragma unroll
        for (int r = 0; r < 8; ++r) tv[r] = ts[r][rr];
        const float* Vr = Vop + rr*DD + lane;
        #pragma unroll
        for (int j = 0; j < 4; ++j) {
            float vv = Vr[64*j];
            #pragma unroll
            for (int r = 0; r < 8; ++r) c2[r][j] = fmaf(tv[r], vv, c2[r][j]);
        }
    }
    #pragma unroll
    for (int r = 0; r < 8; ++r) {
        float* orow_out = outp + (size_t)(row0 + r)*DD;
        #pragma unroll
        for (int j = 0; j < 4; ++j) orow_out[lane + 64*j] = c2[r][j];
    }
}

// ---------------- K5a: BN partial sums (coalesced; thread = channel) ----------------
__global__ __launch_bounds__(256) void k_bnpart(
    const float* __restrict__ outp, float* __restrict__ part)
{
    const int blk = blockIdx.x, t = threadIdx.x;   // 128 blocks x 64 rows
    const float* p = outp + (size_t)blk*64*DD + t;
    float s = 0.f, s2 = 0.f;
    #pragma unroll 4
    for (int r = 0; r < 64; ++r) {
        float v = p[(size_t)r*DD];
        s += v; s2 += v*v;
    }
    part[blk*512 + t]       = s;
    part[blk*512 + 256 + t] = s2;
}

// ---------------- K5b: finalize stats ----------------
__global__ __launch_bounds__(256) void k_bnfin(
    const float* __restrict__ part, float* __restrict__ stats,
    const float* __restrict__ gamma, const float* __restrict__ beta)
{
    const int c = threadIdx.x;
    float s = 0.f, s2 = 0.f;
    for (int j = 0; j < 128; ++j) {
        s  += part[j*512 + c];
        s2 += part[j*512 + 256 + c];
    }
    float mean = s * (1.0f/ROWS);
    float var  = s2 * (1.0f/ROWS) - mean*mean;
    float inv  = rsqrtf(var + 1e-5f);
    float g = gamma[c], be = beta[c];
    stats[c]      = g * inv;
    stats[DD + c] = be - mean * g * inv;
}

// ---------------- K6: apply BN (fp32 out) ----------------
__global__ __launch_bounds__(256) void k_bnapply(
    const float* __restrict__ outp, const float* __restrict__ stats,
    float* __restrict__ out)
{
    const size_t idx = (size_t)blockIdx.x * 256 + threadIdx.x;
    const int c = (int)(idx & (DD-1));
    out[idx] = outp[idx] * stats[c] + stats[DD + c];
}

extern "C" void kernel_launch(void* const* d_in, const int* in_sizes, int n_in,
                              void* d_out, int out_size, void* d_ws, size_t ws_size,
                              hipStream_t stream)
{
    (void)in_sizes; (void)n_in; (void)out_size; (void)ws_size;
    const float* x    = (const float*)d_in[0];
    const float* U_np = (const float*)d_in[1];
    const float* V_np = (const float*)d_in[2];
    const float* b_np = (const float*)d_in[3];
    const float* U_q  = (const float*)d_in[4];
    const float* V_q  = (const float*)d_in[5];
    const float* U_k  = (const float*)d_in[6];
    const float* V_k  = (const float*)d_in[7];
    const float* U_v  = (const float*)d_in[8];
    const float* V_v  = (const float*)d_in[9];
    const float* U_o  = (const float*)d_in[10];
    const float* V_o  = (const float*)d_in[11];
    const float* b_o  = (const float*)d_in[12];
    const float* U_op = (const float*)d_in[13];
    const float* V_op = (const float*)d_in[14];
    const float* b_op = (const float*)d_in[15];
    const float* gamma= (const float*)d_in[16];
    const float* beta = (const float*)d_in[17];

    float* ws  = (float*)d_ws;
    float* out = (float*)d_out;
    const size_t BUF = (size_t)ROWS * DD;     // 2,097,152 floats = 8 MB

    float* h    = out;        // K1 writes, K2 reads, dead after
    float* q    = ws;
    float* k    = ws + BUF;
    float* v    = ws + 2*BUF;
    float* o    = out;        // K3 writes (h dead), K4 reads
    float* outp = q;          // K4 writes (q dead), K5/K6 read
    float* stats= k;          // 512 floats (k dead after attn)
    float* part = v;          // 128*512 floats (v dead after attn)

    k_node_proj<<<ROWS/8, 64, 0, stream>>>(x, U_np, V_np, b_np, h);
    k_qkv<<<ROWS/4, 64, 0, stream>>>(h, U_q, V_q, U_k, V_k, U_v, V_v, q, k, v);
    k_attn<<<BB*HH*32, 256, 0, stream>>>(q, k, v, o);
    k_out_proj<<<ROWS/8, 64, 0, stream>>>(o, U_o, V_o, b_o, U_op, V_op, b_op, outp);
    k_bnpart<<<128, 256, 0, stream>>>(outp, part);
    k_bnfin<<<1, 256, 0, stream>>>(part, stats, gamma, beta);
    k_bnapply<<<ROWS, 256, 0, stream>>>(outp, stats, out);
}